// Round 1
// baseline (623.417 us; speedup 1.0000x reference)
//
#include <hip/hip_runtime.h>
#include <hip/hip_cooperative_groups.h>

namespace cg = cooperative_groups;

#define NF 128
#define OUTF 64

// mark bits
#define M2 1   // x2 needed (layer-2 gather frontier)
#define M1 2   // x1 needed (layer-1 gather frontier)
#define M0 4   // x0 needed (rows for GEMM1)

// capacity caps (expected sizes ~13 / ~180 / ~2600 nodes; huge slack)
#define CAP_F2 2048
#define CAP_E3 4096
#define CAP_F1 32768
#define CAP_E2 65536
#define CAP_F0 131072
#define CAP_E1 262144

// counters: cnt[0]=F2, cnt[1]=E3, cnt[2]=F1, cnt[3]=E2, cnt[4]=F0, cnt[5]=E1

// ---------------------------------------------------------------------------
// Fused cooperative kernel: the whole pipeline in one dispatch.
// 512 blocks x 256 threads, 64KB LDS -> 2 blocks/CU co-resident.
// ---------------------------------------------------------------------------

struct KArgs {
    const float* x;
    const int* srcp;
    const int* dstp;
    int E, n, last;
    const float* W1; const float* b1;
    const float* W2; const float* b2;
    const float* W3; const float* b3;
    const float* fcW; const float* fcb;
    int* deg; int* mark; int* cnt;
    int* F2; int2* E3l; int* F1; int2* E2l; int* F0; int2* E1l;
    float* H; float* aggA; float* aggB;
    float* out;
};

// one backward-BFS level (edge scan + self-loop frontier propagation)
__device__ __forceinline__ void bfs_level(
    const int* __restrict__ src, const int* __restrict__ dst, int E,
    int* __restrict__ mark, int checkBit, int setBit,
    int2* __restrict__ Elist, int Ecap, int* __restrict__ eCnt,
    int* __restrict__ Flist, int Fcap, int* __restrict__ fCnt,
    const int* __restrict__ selfList, int selfCnt,
    int gtid, int gstride)
{
    for (int i = gtid; i < selfCnt; i += gstride) {
        int v = selfList[i];
        if (!(atomicOr(&mark[v], setBit) & setBit)) {
            int p = atomicAdd(fCnt, 1);
            if (p < Fcap) Flist[p] = v;
        }
    }
    for (int i = gtid; i < E; i += gstride) {
        int d = dst[i];
        if (mark[d] & checkBit) {
            int s = src[i];
            int p = atomicAdd(eCnt, 1);
            if (p < Ecap) Elist[p] = make_int2(s, d);
            if (!(atomicOr(&mark[s], setBit) & setBit)) {
                int q = atomicAdd(fCnt, 1);
                if (q < Fcap) Flist[q] = s;
            }
        }
    }
}

// row-list GEMM phase. USE_LDS: stage W in LDS (worth it when many rows/block);
// else read W straight from L2 (few rows -> staging in 512 blocks is waste).
template<bool USE_LDS>
__device__ __forceinline__ void gemm_phase(
    const int* __restrict__ list, int rows,
    const float* __restrict__ Xin, const float* __restrict__ bias,
    const float* __restrict__ W, const int* __restrict__ deg,
    const int* __restrict__ mark, int aggBit,
    float* __restrict__ H, float* __restrict__ AGG,
    float (&wsm)[128][128])
{
    if ((int)blockIdx.x * 4 >= rows) return;   // block has no row: skip (incl. staging)
    const int t = threadIdx.x;
    if (USE_LDS) {
        const float4* W4 = (const float4*)W;
        float4* S4 = (float4*)&wsm[0][0];
        #pragma unroll
        for (int it = 0; it < 16; ++it) S4[it * 256 + t] = W4[it * 256 + t];
        __syncthreads();
    }
    const int wave = t >> 6, lane = t & 63;
    for (int base = blockIdx.x * 4; base < rows; base += gridDim.x * 4) {
        int r = base + wave;
        if (r >= rows) continue;
        int v = list[r];
        size_t off = (size_t)v * NF;

        float x0, x1;
        if (bias) {
            x0 = fmaxf(Xin[off + lane]      + bias[lane],      0.f);
            x1 = fmaxf(Xin[off + lane + 64] + bias[lane + 64], 0.f);
        } else {
            x0 = Xin[off + lane];
            x1 = Xin[off + lane + 64];
        }

        float a0 = 0.f, a1 = 0.f;
        if (USE_LDS) {
            #pragma unroll 16
            for (int k = 0; k < 64; ++k) {
                float xk = __shfl(x0, k);
                a0 += xk * wsm[k][lane];
                a1 += xk * wsm[k][lane + 64];
            }
            #pragma unroll 16
            for (int k = 0; k < 64; ++k) {
                float xk = __shfl(x1, k);
                a0 += xk * wsm[k + 64][lane];
                a1 += xk * wsm[k + 64][lane + 64];
            }
        } else {
            #pragma unroll 8
            for (int k = 0; k < 64; ++k) {
                float xk = __shfl(x0, k);
                a0 += xk * W[k * NF + lane];
                a1 += xk * W[k * NF + lane + 64];
            }
            #pragma unroll 8
            for (int k = 0; k < 64; ++k) {
                float xk = __shfl(x1, k);
                a0 += xk * W[(k + 64) * NF + lane];
                a1 += xk * W[(k + 64) * NF + lane + 64];
            }
        }

        H[off + lane]      = a0;
        H[off + lane + 64] = a1;

        if (mark[v] & aggBit) {   // init AGG with self-loop term
            float di = rsqrtf(1.0f + (float)deg[v]);
            float s2 = di * di;
            AGG[off + lane]      = a0 * s2;
            AGG[off + lane + 64] = a1 * s2;
        }
    }
}

// edge-list scatter: AGG[d] += dinv[s]*dinv[d] * H[s]  (128-thread groups)
__device__ __forceinline__ void scat_phase(
    const int2* __restrict__ Elist, int ecnt,
    const int* __restrict__ deg, const float* __restrict__ H,
    float* __restrict__ AGG, int gtid, int gstride)
{
    int grp = gtid >> 7, f = gtid & 127, ngrp = gstride >> 7;
    for (int i = grp; i < ecnt; i += ngrp) {
        int2 e = Elist[i];
        float w = rsqrtf(1.f + (float)deg[e.x]) * rsqrtf(1.f + (float)deg[e.y]);
        atomicAdd(&AGG[(size_t)e.y * NF + f], H[(size_t)e.x * NF + f] * w);
    }
}

__global__ __launch_bounds__(256, 2) void k_fused(KArgs a)
{
    __shared__ float wsm[128][128];   // 64 KB: W staging; reused by tail FC
    cg::grid_group grid = cg::this_grid();
    const int gtid = blockIdx.x * blockDim.x + threadIdx.x;
    const int gstride = gridDim.x * blockDim.x;
    const int E = a.E, n = a.n, last = a.last;

    // ---- P0: zero deg / mark / cnt (replaces hipMemsetAsync) ----
    for (int i = gtid; i < n; i += gstride) { a.deg[i] = 0; a.mark[i] = 0; }
    if (gtid < 64) a.cnt[gtid] = 0;
    grid.sync();

    // ---- P1: BFS level 1 (dst == last) + UNCONDITIONAL in-degree count ----
    // counting deg for all nodes here removes the separate k_degm edge scan
    if (gtid == 0) {
        if (!(atomicOr(&a.mark[last], M2) & M2)) {
            int p = atomicAdd(&a.cnt[0], 1);
            if (p < CAP_F2) a.F2[p] = last;
        }
    }
    for (int i = gtid; i < E; i += gstride) {
        int d = a.dstp[i];
        atomicAdd(&a.deg[d], 1);
        if (d == last) {
            int s = a.srcp[i];
            int p = atomicAdd(&a.cnt[1], 1);
            if (p < CAP_E3) a.E3l[p] = make_int2(s, d);
            if (!(atomicOr(&a.mark[s], M2) & M2)) {
                int q = atomicAdd(&a.cnt[0], 1);
                if (q < CAP_F2) a.F2[q] = s;
            }
        }
    }
    grid.sync();

    // ---- P2: BFS level 2 (M2 -> M1), self-prop F2 into F1 ----
    bfs_level(a.srcp, a.dstp, E, a.mark, M2, M1,
              a.E2l, CAP_E2, &a.cnt[3], a.F1, CAP_F1, &a.cnt[2],
              a.F2, min(a.cnt[0], CAP_F2), gtid, gstride);
    grid.sync();

    // ---- P3: BFS level 3 (M1 -> M0), self-prop F1 into F0 ----
    bfs_level(a.srcp, a.dstp, E, a.mark, M1, M0,
              a.E1l, CAP_E1, &a.cnt[5], a.F0, CAP_F0, &a.cnt[4],
              a.F1, min(a.cnt[2], CAP_F1), gtid, gstride);
    grid.sync();

    // ---- P4: layer-1 GEMM on F0 rows (W1 in LDS; ~2600 rows) ----
    gemm_phase<true>(a.F0, min(a.cnt[4], CAP_F0), a.x, nullptr, a.W1,
                     a.deg, a.mark, M1, a.H, a.aggA, wsm);
    grid.sync();

    // ---- P5: scatter E1 into aggA ----
    scat_phase(a.E1l, min(a.cnt[5], CAP_E1), a.deg, a.H, a.aggA, gtid, gstride);
    grid.sync();

    // ---- P6: layer-2 GEMM on F1 rows (~180 rows; W2 direct from L2) ----
    gemm_phase<false>(a.F1, min(a.cnt[2], CAP_F1), a.aggA, a.b1, a.W2,
                      a.deg, a.mark, M2, a.H, a.aggB, wsm);
    grid.sync();

    // ---- P7: scatter E2 into aggB ----
    scat_phase(a.E2l, min(a.cnt[3], CAP_E2), a.deg, a.H, a.aggB, gtid, gstride);
    grid.sync();

    // ---- P8 (block 0 only): layer-3 GEMM (~13 rows) + E3 reduce + FC ----
    // All E3 edges target agg[last]: accumulate in registers, no atomics,
    // no extra grid syncs.
    if (blockIdx.x == 0) {
        const int t = threadIdx.x;
        const int wave = t >> 6, lane = t & 63;
        int rows = min(a.cnt[0], CAP_F2);
        for (int r = wave; r < rows; r += 4) {
            int v = a.F2[r];
            size_t off = (size_t)v * NF;
            float x0 = fmaxf(a.aggB[off + lane]      + a.b2[lane],      0.f);
            float x1 = fmaxf(a.aggB[off + lane + 64] + a.b2[lane + 64], 0.f);
            float a0 = 0.f, a1 = 0.f;
            #pragma unroll 8
            for (int k = 0; k < 64; ++k) {
                float xk = __shfl(x0, k);
                a0 += xk * a.W3[k * NF + lane];
                a1 += xk * a.W3[k * NF + lane + 64];
            }
            #pragma unroll 8
            for (int k = 0; k < 64; ++k) {
                float xk = __shfl(x1, k);
                a0 += xk * a.W3[(k + 64) * NF + lane];
                a1 += xk * a.W3[(k + 64) * NF + lane + 64];
            }
            a.H[off + lane]      = a0;
            a.H[off + lane + 64] = a1;
        }
        __syncthreads();
        if (t < NF) {
            float dl = rsqrtf(1.f + (float)a.deg[last]);
            float acc = dl * dl * a.H[(size_t)last * NF + t];   // self-loop term
            int e3 = min(a.cnt[1], CAP_E3);
            for (int i = 0; i < e3; ++i) {
                int s = a.E3l[i].x;
                acc += rsqrtf(1.f + (float)a.deg[s]) * dl * a.H[(size_t)s * NF + t];
            }
            wsm[0][t] = fmaxf(acc + a.b3[t], 0.f);
        }
        __syncthreads();
        if (t < OUTF) {
            float acc = a.fcb[t];
            #pragma unroll 16
            for (int k = 0; k < NF; ++k) acc += wsm[0][k] * a.fcW[k * OUTF + t];
            a.out[t] = acc;
        }
    }
}

// ---------------------------------------------------------------------------
// Fallback: the proven 15-kernel pipeline (used only if cooperative launch
// is rejected by the runtime / graph capture).
// ---------------------------------------------------------------------------

__global__ void k_seed(int* __restrict__ mark, int* __restrict__ F2,
                       int* __restrict__ cnt, int last) {
    if (threadIdx.x == 0) {
        mark[last] = M2;
        F2[0] = last;
        cnt[0] = 1;
    }
}

__global__ void k_mark(const int* __restrict__ src, const int* __restrict__ dst, int E,
                       int* __restrict__ mark, int checkBit, int setBit, int last,
                       int2* __restrict__ Elist, int Ecap, int* __restrict__ eCnt,
                       int* __restrict__ Flist, int Fcap, int* __restrict__ fCnt,
                       const int* __restrict__ selfList, const int* __restrict__ selfCnt,
                       int selfCap)
{
    int i = blockIdx.x * blockDim.x + threadIdx.x;

    if (selfList) {
        int sc = *selfCnt; if (sc > selfCap) sc = selfCap;
        if (i < sc) {
            int v = selfList[i];
            if (!(atomicOr(&mark[v], setBit) & setBit)) {
                int p = atomicAdd(fCnt, 1);
                if (p < Fcap) Flist[p] = v;
            }
        }
    }
    if (i < E) {
        int d = dst[i];
        bool hit = checkBit ? ((mark[d] & checkBit) != 0) : (d == last);
        if (hit) {
            int s = src[i];
            int p = atomicAdd(eCnt, 1);
            if (p < Ecap) Elist[p] = make_int2(s, d);
            if (!(atomicOr(&mark[s], setBit) & setBit)) {
                int q = atomicAdd(fCnt, 1);
                if (q < Fcap) Flist[q] = s;
            }
        }
    }
}

__global__ void k_degm(const int* __restrict__ dst, const int* __restrict__ mark,
                       int* __restrict__ deg, int E) {
    int i = blockIdx.x * blockDim.x + threadIdx.x;
    if (i < E) {
        int d = dst[i];
        if (mark[d]) atomicAdd(&deg[d], 1);
    }
}

__global__ void k_dinvm(const int* __restrict__ mark, const int* __restrict__ deg,
                        float* __restrict__ dinv, int n) {
    int i = blockIdx.x * blockDim.x + threadIdx.x;
    if (i < n && mark[i]) dinv[i] = rsqrtf(1.0f + (float)deg[i]);
}

__global__ __launch_bounds__(256) void k_gemm_rows(
    const int* __restrict__ list, const int* __restrict__ cntPtr, int cap,
    const float* __restrict__ Xin, const float* __restrict__ bias,
    const float* __restrict__ W, const float* __restrict__ dinv,
    const int* __restrict__ mark, int aggBit, int last,
    float* __restrict__ H, float* __restrict__ AGG)
{
    __shared__ float wsm[128][128];
    const int t = threadIdx.x;

    {
        const float4* W4 = (const float4*)W;
        float4* S4 = (float4*)&wsm[0][0];
        #pragma unroll
        for (int it = 0; it < 16; ++it) S4[it * 256 + t] = W4[it * 256 + t];
    }
    __syncthreads();

    int cnt = *cntPtr; if (cnt > cap) cnt = cap;
    const int wave = t >> 6, lane = t & 63;

    for (int base = blockIdx.x * 4; base < cnt; base += gridDim.x * 4) {
        int r = base + wave;
        if (r >= cnt) continue;
        int v = list[r];
        size_t off = (size_t)v * NF;

        float x0, x1;
        if (bias) {
            x0 = fmaxf(Xin[off + lane]      + bias[lane],      0.f);
            x1 = fmaxf(Xin[off + lane + 64] + bias[lane + 64], 0.f);
        } else {
            x0 = Xin[off + lane];
            x1 = Xin[off + lane + 64];
        }

        float a0 = 0.f, a1 = 0.f;
        #pragma unroll 16
        for (int k = 0; k < 64; ++k) {
            float xk = __shfl(x0, k);
            a0 += xk * wsm[k][lane];
            a1 += xk * wsm[k][lane + 64];
        }
        #pragma unroll 16
        for (int k = 0; k < 64; ++k) {
            float xk = __shfl(x1, k);
            a0 += xk * wsm[k + 64][lane];
            a1 += xk * wsm[k + 64][lane + 64];
        }

        H[off + lane]      = a0;
        H[off + lane + 64] = a1;

        bool doAgg = (mark ? ((mark[v] & aggBit) != 0) : false) || (v == last);
        if (doAgg) {
            float di = dinv[v], s2 = di * di;
            AGG[off + lane]      = a0 * s2;
            AGG[off + lane + 64] = a1 * s2;
        }
    }
}

__global__ void k_scat(const int2* __restrict__ list, const int* __restrict__ cntPtr, int cap,
                       const float* __restrict__ dinv, const float* __restrict__ H,
                       float* __restrict__ AGG)
{
    int cnt = *cntPtr; if (cnt > cap) cnt = cap;
    int t = threadIdx.x;
    for (int i = blockIdx.x; i < cnt; i += gridDim.x) {
        int2 e = list[i];
        float w = dinv[e.x] * dinv[e.y];
        atomicAdd(&AGG[(size_t)e.y * NF + t], H[(size_t)e.x * NF + t] * w);
    }
}

__global__ void k_fc(const float* __restrict__ AGG3, const float* __restrict__ b3,
                     const float* __restrict__ fcW, const float* __restrict__ fcb,
                     float* __restrict__ out, int last)
{
    __shared__ float xrow[NF];
    int j = threadIdx.x;
    size_t off = (size_t)last * NF;
    xrow[j]      = fmaxf(AGG3[off + j]      + b3[j],      0.f);
    xrow[j + 64] = fmaxf(AGG3[off + j + 64] + b3[j + 64], 0.f);
    __syncthreads();
    float acc = fcb[j];
    #pragma unroll 16
    for (int k = 0; k < NF; ++k) acc += xrow[k] * fcW[k * OUTF + j];
    out[j] = acc;
}

// ---------------------------------------------------------------------------

extern "C" void kernel_launch(void* const* d_in, const int* in_sizes, int n_in,
                              void* d_out, int out_size, void* d_ws, size_t ws_size,
                              hipStream_t stream)
{
    const float* x    = (const float*)d_in[0];
    const int*   ei   = (const int*)d_in[1];
    const float* W1   = (const float*)d_in[2];
    const float* b1   = (const float*)d_in[3];
    const float* W2   = (const float*)d_in[4];
    const float* b2   = (const float*)d_in[5];
    const float* W3   = (const float*)d_in[6];
    const float* b3   = (const float*)d_in[7];
    const float* fcW  = (const float*)d_in[8];
    const float* fcb  = (const float*)d_in[9];
    float* out = (float*)d_out;

    const int n = in_sizes[0] / NF;       // 50000
    const int E = in_sizes[1] / 2;        // 600000
    const int* src = ei;
    const int* dst = ei + E;
    const int last = n - 1;

    char* wp = (char*)d_ws;
    auto alloc = [&](size_t bytes) -> void* {
        void* r = (void*)wp;
        wp += (bytes + 255) & ~(size_t)255;
        return r;
    };
    int*   deg  = (int*)alloc((size_t)n * 4);
    int*   mark = (int*)alloc((size_t)n * 4);
    int*   cnt  = (int*)alloc(64 * 4);
    size_t zbytes = (char*)wp - (char*)deg;

    float* dinv = (float*)alloc((size_t)n * 4);      // fallback path only
    int*   F2   = (int*) alloc(CAP_F2 * 4);
    int2*  E3   = (int2*)alloc(CAP_E3 * 8);
    int*   F1   = (int*) alloc(CAP_F1 * 4);
    int2*  E2   = (int2*)alloc(CAP_E2 * 8);
    int*   F0   = (int*) alloc(CAP_F0 * 4);
    int2*  E1   = (int2*)alloc(CAP_E1 * 8);
    float* H    = (float*)alloc((size_t)n * NF * 4);
    float* aggA = (float*)alloc((size_t)n * NF * 4);
    float* aggB = (float*)alloc((size_t)n * NF * 4);

    // ---- try the single cooperative kernel ----
    static int coopState = -2;   // -2 untested, -1 unsupported, >0 grid size
    if (coopState != -1) {
        if (coopState == -2) {
            int perCU = 0;
            if (hipOccupancyMaxActiveBlocksPerMultiprocessor(&perCU, k_fused, 256, 0)
                    != hipSuccess || perCU < 1)
                perCU = 1;
            long g = (long)perCU * 256;   // 256 CUs on MI355X
            if (g > 512) g = 512;         // 64KB LDS -> 2 blocks/CU max anyway
            coopState = (int)g;
        }
        KArgs ha;
        ha.x = x; ha.srcp = src; ha.dstp = dst;
        ha.E = E; ha.n = n; ha.last = last;
        ha.W1 = W1; ha.b1 = b1; ha.W2 = W2; ha.b2 = b2;
        ha.W3 = W3; ha.b3 = b3; ha.fcW = fcW; ha.fcb = fcb;
        ha.deg = deg; ha.mark = mark; ha.cnt = cnt;
        ha.F2 = F2; ha.E3l = E3; ha.F1 = F1; ha.E2l = E2; ha.F0 = F0; ha.E1l = E1;
        ha.H = H; ha.aggA = aggA; ha.aggB = aggB; ha.out = out;

        void* params[1] = { (void*)&ha };
        hipError_t err = hipLaunchCooperativeKernel(k_fused, dim3(coopState), dim3(256),
                                                    params, 0u, stream);
        if (err == hipSuccess) return;
        coopState = -1;          // remember: coop not available; use fallback
        (void)hipGetLastError(); // clear error state
    }

    // ---- fallback: original multi-kernel pipeline ----
    const int B  = 256;
    const int EB = (E + B - 1) / B;
    const int NB = (n + B - 1) / B;

    hipMemsetAsync(deg, 0, zbytes, stream);
    k_seed<<<1, 64, 0, stream>>>(mark, F2, cnt, last);

    k_mark<<<EB, B, 0, stream>>>(src, dst, E, mark, 0,  M2, last,
                                 E3, CAP_E3, &cnt[1], F2, CAP_F2, &cnt[0],
                                 nullptr, nullptr, 0);
    k_mark<<<EB, B, 0, stream>>>(src, dst, E, mark, M2, M1, last,
                                 E2, CAP_E2, &cnt[3], F1, CAP_F1, &cnt[2],
                                 F2, &cnt[0], CAP_F2);
    k_mark<<<EB, B, 0, stream>>>(src, dst, E, mark, M1, M0, last,
                                 E1, CAP_E1, &cnt[5], F0, CAP_F0, &cnt[4],
                                 F1, &cnt[2], CAP_F1);

    k_degm <<<EB, B, 0, stream>>>(dst, mark, deg, E);
    k_dinvm<<<NB, B, 0, stream>>>(mark, deg, dinv, n);

    k_gemm_rows<<<384, B, 0, stream>>>(F0, &cnt[4], CAP_F0, x, nullptr, W1,
                                       dinv, mark, M1, -1, H, aggA);
    k_scat<<<2048, 128, 0, stream>>>(E1, &cnt[5], CAP_E1, dinv, H, aggA);

    k_gemm_rows<<<384, B, 0, stream>>>(F1, &cnt[2], CAP_F1, aggA, b1, W2,
                                       dinv, mark, M2, -1, H, aggB);
    k_scat<<<2048, 128, 0, stream>>>(E2, &cnt[3], CAP_E2, dinv, H, aggB);

    k_gemm_rows<<<384, B, 0, stream>>>(F2, &cnt[0], CAP_F2, aggB, b2, W3,
                                       dinv, nullptr, 0, last, H, aggA);
    k_scat<<<2048, 128, 0, stream>>>(E3, &cnt[1], CAP_E3, dinv, H, aggA);

    k_fc<<<1, 64, 0, stream>>>(aggA, b3, fcW, fcb, out, last);
}

// Round 2
// 530.489 us; speedup vs baseline: 1.1752x; 1.1752x over previous
//
#include <hip/hip_runtime.h>

#define NF 128
#define OUTF 64

// mark bits
#define M2 1   // layer-2 gather frontier
#define M1 2   // layer-1 gather frontier
#define M0 4   // rows for GEMM1

// capacity caps (expected ~13 / ~180 / ~2600 nodes; huge slack)
#define CAP_F2 2048
#define CAP_E3 4096
#define CAP_F1 32768
#define CAP_E2 65536
#define CAP_F0 131072
#define CAP_E1 262144

// cnt[0]=F2, cnt[1]=E3, cnt[2]=F1, cnt[3]=E2, cnt[4]=F0, cnt[5]=E1
// cnt[64 + 16*i] = grid-barrier slot i (line-spaced), zeroed by host memset

struct KArgs {
    const float* x;
    const int* srcp;
    const int* dstp;
    int E, n, last;
    const float* W1; const float* b1;
    const float* W2; const float* b2;
    const float* W3; const float* b3;
    const float* fcW; const float* fcb;
    int* deg; int* mark; int* cnt; int* bar;
    int* F2; int2* E3l; int* F1; int2* E2l; int* F0; int2* E1l;
    float* H; float* aggA; float* aggB;
    float* out;
};

// -------- hand-rolled one-shot grid barrier (slot must start at 0) --------
__device__ __forceinline__ void gbar(int* slot) {
    __syncthreads();                       // compiler drains vmcnt before s_barrier
    if (threadIdx.x == 0) {
        __threadfence();                   // release: L2 writeback to coherence point
        atomicAdd(slot, 1);                // device-scope arrive
        while (__hip_atomic_load(slot, __ATOMIC_RELAXED,
                                 __HIP_MEMORY_SCOPE_AGENT) < (int)gridDim.x)
            __builtin_amdgcn_s_sleep(1);
        __threadfence();                   // acquire: invalidate so we see remote writes
    }
    __syncthreads();
}

// -------- P1: unconditional in-degree + level-1 (dst==last) collection --------
__device__ __forceinline__ void p1_hit(const KArgs& a, int d, int i) {
    atomicAdd(&a.deg[d], 1);
    if (d == a.last) {
        int s = a.srcp[i];
        int p = atomicAdd(&a.cnt[1], 1);
        if (p < CAP_E3) a.E3l[p] = make_int2(s, d);
        if (!(atomicOr(&a.mark[s], M2) & M2)) {
            int q = atomicAdd(&a.cnt[0], 1);
            if (q < CAP_F2) a.F2[q] = s;
        }
    }
}

// -------- BFS level hit: marked dst -> record edge, mark+append src --------
__device__ __forceinline__ void bfs_hit(
    const KArgs& a, int d, int i, int checkBit, int setBit,
    int2* El, int Ecap, int* eCnt, int* Fl, int Fcap, int* fCnt)
{
    if (a.mark[d] & checkBit) {
        int s = a.srcp[i];
        int p = atomicAdd(eCnt, 1);
        if (p < Ecap) El[p] = make_int2(s, d);
        if (!(atomicOr(&a.mark[s], setBit) & setBit)) {
            int q = atomicAdd(fCnt, 1);
            if (q < Fcap) Fl[q] = s;
        }
    }
}

// row-list GEMM phase. USE_LDS: stage W in LDS; else read W from L2.
// NO early return — every block must reach the following barrier.
template<bool USE_LDS>
__device__ __forceinline__ void gemm_phase(
    const int* __restrict__ list, int rows,
    const float* __restrict__ Xin, const float* __restrict__ bias,
    const float* __restrict__ W, const int* __restrict__ deg,
    const int* __restrict__ mark, int aggBit,
    float* __restrict__ H, float* __restrict__ AGG,
    float (&wsm)[128][128])
{
    const bool active = ((int)blockIdx.x * 4 < rows);   // block-uniform
    const int t = threadIdx.x;
    if (USE_LDS && active) {
        const float4* W4 = (const float4*)W;
        float4* S4 = (float4*)&wsm[0][0];
        #pragma unroll
        for (int it = 0; it < 16; ++it) S4[it * 256 + t] = W4[it * 256 + t];
        __syncthreads();
    }
    if (!active) return;   // inlined: just skips to the caller's gbar
    const int wave = t >> 6, lane = t & 63;
    for (int base = blockIdx.x * 4; base < rows; base += gridDim.x * 4) {
        int r = base + wave;
        if (r >= rows) continue;
        int v = list[r];
        size_t off = (size_t)v * NF;

        float x0, x1;
        if (bias) {
            x0 = fmaxf(Xin[off + lane]      + bias[lane],      0.f);
            x1 = fmaxf(Xin[off + lane + 64] + bias[lane + 64], 0.f);
        } else {
            x0 = Xin[off + lane];
            x1 = Xin[off + lane + 64];
        }

        float a0 = 0.f, a1 = 0.f;
        if (USE_LDS) {
            #pragma unroll 16
            for (int k = 0; k < 64; ++k) {
                float xk = __shfl(x0, k);
                a0 += xk * wsm[k][lane];
                a1 += xk * wsm[k][lane + 64];
            }
            #pragma unroll 16
            for (int k = 0; k < 64; ++k) {
                float xk = __shfl(x1, k);
                a0 += xk * wsm[k + 64][lane];
                a1 += xk * wsm[k + 64][lane + 64];
            }
        } else {
            #pragma unroll 8
            for (int k = 0; k < 64; ++k) {
                float xk = __shfl(x0, k);
                a0 += xk * W[k * NF + lane];
                a1 += xk * W[k * NF + lane + 64];
            }
            #pragma unroll 8
            for (int k = 0; k < 64; ++k) {
                float xk = __shfl(x1, k);
                a0 += xk * W[(k + 64) * NF + lane];
                a1 += xk * W[(k + 64) * NF + lane + 64];
            }
        }

        H[off + lane]      = a0;
        H[off + lane + 64] = a1;

        if (mark[v] & aggBit) {   // init AGG with self-loop term
            float di = rsqrtf(1.0f + (float)deg[v]);
            float s2 = di * di;
            AGG[off + lane]      = a0 * s2;
            AGG[off + lane + 64] = a1 * s2;
        }
    }
}

__device__ __forceinline__ void scat_phase(
    const int2* __restrict__ Elist, int ecnt,
    const int* __restrict__ deg, const float* __restrict__ H,
    float* __restrict__ AGG, int gtid, int gstride)
{
    int grp = gtid >> 7, f = gtid & 127, ngrp = gstride >> 7;
    for (int i = grp; i < ecnt; i += ngrp) {
        int2 e = Elist[i];
        float w = rsqrtf(1.f + (float)deg[e.x]) * rsqrtf(1.f + (float)deg[e.y]);
        atomicAdd(&AGG[(size_t)e.y * NF + f], H[(size_t)e.x * NF + f] * w);
    }
}

__global__ __launch_bounds__(256, 2) void k_fused(KArgs a)
{
    __shared__ float wsm[128][128];   // 64 KB: W staging; reused by tail FC
    const int gtid = blockIdx.x * blockDim.x + threadIdx.x;
    const int gstride = gridDim.x * blockDim.x;
    const int E = a.E;
    int* bar = a.bar;

    // ---- P1: seed + unconditional deg count + level-1 edge collection ----
    if (gtid == 0) {
        if (!(atomicOr(&a.mark[a.last], M2) & M2)) {
            int p = atomicAdd(&a.cnt[0], 1);
            if (p < CAP_F2) a.F2[p] = a.last;
        }
    }
    const bool vec4 = (((uintptr_t)a.dstp & 15) == 0);
    if (vec4) {
        const int4* d4p = (const int4*)a.dstp;
        int nq = E >> 2;
        for (int q = gtid; q < nq; q += gstride) {
            int4 d4 = d4p[q];
            int i = q << 2;
            p1_hit(a, d4.x, i);
            p1_hit(a, d4.y, i + 1);
            p1_hit(a, d4.z, i + 2);
            p1_hit(a, d4.w, i + 3);
        }
        for (int i = (nq << 2) + gtid; i < E; i += gstride) p1_hit(a, a.dstp[i], i);
    } else {
        for (int i = gtid; i < E; i += gstride) p1_hit(a, a.dstp[i], i);
    }
    gbar(&bar[0]);

    // ---- P2: level 2 (M2 -> M1) + self-prop F2 into F1 ----
    {
        int sc = min(a.cnt[0], CAP_F2);
        for (int i = gtid; i < sc; i += gstride) {
            int v = a.F2[i];
            if (!(atomicOr(&a.mark[v], M1) & M1)) {
                int p = atomicAdd(&a.cnt[2], 1);
                if (p < CAP_F1) a.F1[p] = v;
            }
        }
        if (vec4) {
            const int4* d4p = (const int4*)a.dstp;
            int nq = E >> 2;
            for (int q = gtid; q < nq; q += gstride) {
                int4 d4 = d4p[q];
                int i = q << 2;
                bfs_hit(a, d4.x, i,     M2, M1, a.E2l, CAP_E2, &a.cnt[3], a.F1, CAP_F1, &a.cnt[2]);
                bfs_hit(a, d4.y, i + 1, M2, M1, a.E2l, CAP_E2, &a.cnt[3], a.F1, CAP_F1, &a.cnt[2]);
                bfs_hit(a, d4.z, i + 2, M2, M1, a.E2l, CAP_E2, &a.cnt[3], a.F1, CAP_F1, &a.cnt[2]);
                bfs_hit(a, d4.w, i + 3, M2, M1, a.E2l, CAP_E2, &a.cnt[3], a.F1, CAP_F1, &a.cnt[2]);
            }
            for (int i = (nq << 2) + gtid; i < E; i += gstride)
                bfs_hit(a, a.dstp[i], i, M2, M1, a.E2l, CAP_E2, &a.cnt[3], a.F1, CAP_F1, &a.cnt[2]);
        } else {
            for (int i = gtid; i < E; i += gstride)
                bfs_hit(a, a.dstp[i], i, M2, M1, a.E2l, CAP_E2, &a.cnt[3], a.F1, CAP_F1, &a.cnt[2]);
        }
    }
    gbar(&bar[16]);

    // ---- P3: level 3 (M1 -> M0) + self-prop F1 into F0 ----
    {
        int sc = min(a.cnt[2], CAP_F1);
        for (int i = gtid; i < sc; i += gstride) {
            int v = a.F1[i];
            if (!(atomicOr(&a.mark[v], M0) & M0)) {
                int p = atomicAdd(&a.cnt[4], 1);
                if (p < CAP_F0) a.F0[p] = v;
            }
        }
        if (vec4) {
            const int4* d4p = (const int4*)a.dstp;
            int nq = E >> 2;
            for (int q = gtid; q < nq; q += gstride) {
                int4 d4 = d4p[q];
                int i = q << 2;
                bfs_hit(a, d4.x, i,     M1, M0, a.E1l, CAP_E1, &a.cnt[5], a.F0, CAP_F0, &a.cnt[4]);
                bfs_hit(a, d4.y, i + 1, M1, M0, a.E1l, CAP_E1, &a.cnt[5], a.F0, CAP_F0, &a.cnt[4]);
                bfs_hit(a, d4.z, i + 2, M1, M0, a.E1l, CAP_E1, &a.cnt[5], a.F0, CAP_F0, &a.cnt[4]);
                bfs_hit(a, d4.w, i + 3, M1, M0, a.E1l, CAP_E1, &a.cnt[5], a.F0, CAP_F0, &a.cnt[4]);
            }
            for (int i = (nq << 2) + gtid; i < E; i += gstride)
                bfs_hit(a, a.dstp[i], i, M1, M0, a.E1l, CAP_E1, &a.cnt[5], a.F0, CAP_F0, &a.cnt[4]);
        } else {
            for (int i = gtid; i < E; i += gstride)
                bfs_hit(a, a.dstp[i], i, M1, M0, a.E1l, CAP_E1, &a.cnt[5], a.F0, CAP_F0, &a.cnt[4]);
        }
    }
    gbar(&bar[32]);

    // ---- P4: layer-1 GEMM on F0 rows (W1 in LDS) ----
    gemm_phase<true>(a.F0, min(a.cnt[4], CAP_F0), a.x, nullptr, a.W1,
                     a.deg, a.mark, M1, a.H, a.aggA, wsm);
    gbar(&bar[48]);

    // ---- P5: scatter E1 into aggA ----
    scat_phase(a.E1l, min(a.cnt[5], CAP_E1), a.deg, a.H, a.aggA, gtid, gstride);
    gbar(&bar[64]);

    // ---- P6: layer-2 GEMM on F1 rows (W2 from L2) ----
    gemm_phase<false>(a.F1, min(a.cnt[2], CAP_F1), a.aggA, a.b1, a.W2,
                      a.deg, a.mark, M2, a.H, a.aggB, wsm);
    gbar(&bar[80]);

    // ---- P7: scatter E2 into aggB ----
    scat_phase(a.E2l, min(a.cnt[3], CAP_E2), a.deg, a.H, a.aggB, gtid, gstride);
    gbar(&bar[96]);

    // ---- P8 (block 0 only): layer-3 GEMM + E3 register-reduce + FC ----
    if (blockIdx.x == 0) {
        const int t = threadIdx.x;
        const int wave = t >> 6, lane = t & 63;
        int rows = min(a.cnt[0], CAP_F2);
        for (int r = wave; r < rows; r += 4) {
            int v = a.F2[r];
            size_t off = (size_t)v * NF;
            float x0 = fmaxf(a.aggB[off + lane]      + a.b2[lane],      0.f);
            float x1 = fmaxf(a.aggB[off + lane + 64] + a.b2[lane + 64], 0.f);
            float a0 = 0.f, a1 = 0.f;
            #pragma unroll 8
            for (int k = 0; k < 64; ++k) {
                float xk = __shfl(x0, k);
                a0 += xk * a.W3[k * NF + lane];
                a1 += xk * a.W3[k * NF + lane + 64];
            }
            #pragma unroll 8
            for (int k = 0; k < 64; ++k) {
                float xk = __shfl(x1, k);
                a0 += xk * a.W3[(k + 64) * NF + lane];
                a1 += xk * a.W3[(k + 64) * NF + lane + 64];
            }
            a.H[off + lane]      = a0;
            a.H[off + lane + 64] = a1;
        }
        __syncthreads();
        if (t < NF) {
            float dl = rsqrtf(1.f + (float)a.deg[a.last]);
            float acc = dl * dl * a.H[(size_t)a.last * NF + t];   // self-loop term
            int e3 = min(a.cnt[1], CAP_E3);
            for (int i = 0; i < e3; ++i) {
                int s = a.E3l[i].x;
                acc += rsqrtf(1.f + (float)a.deg[s]) * dl * a.H[(size_t)s * NF + t];
            }
            wsm[0][t] = fmaxf(acc + a.b3[t], 0.f);
        }
        __syncthreads();
        if (t < OUTF) {
            float acc = a.fcb[t];
            #pragma unroll 16
            for (int k = 0; k < NF; ++k) acc += wsm[0][k] * a.fcW[k * OUTF + t];
            a.out[t] = acc;
        }
    }
}

// ---------------------------------------------------------------------------
// Fallback: proven multi-kernel pipeline (used only if coop launch rejected)
// ---------------------------------------------------------------------------

__global__ void k_seed(int* __restrict__ mark, int* __restrict__ F2,
                       int* __restrict__ cnt, int last) {
    if (threadIdx.x == 0) {
        mark[last] = M2;
        F2[0] = last;
        cnt[0] = 1;
    }
}

__global__ void k_mark(const int* __restrict__ src, const int* __restrict__ dst, int E,
                       int* __restrict__ mark, int checkBit, int setBit, int last,
                       int2* __restrict__ Elist, int Ecap, int* __restrict__ eCnt,
                       int* __restrict__ Flist, int Fcap, int* __restrict__ fCnt,
                       const int* __restrict__ selfList, const int* __restrict__ selfCnt,
                       int selfCap)
{
    int i = blockIdx.x * blockDim.x + threadIdx.x;

    if (selfList) {
        int sc = *selfCnt; if (sc > selfCap) sc = selfCap;
        if (i < sc) {
            int v = selfList[i];
            if (!(atomicOr(&mark[v], setBit) & setBit)) {
                int p = atomicAdd(fCnt, 1);
                if (p < Fcap) Flist[p] = v;
            }
        }
    }
    if (i < E) {
        int d = dst[i];
        bool hit = checkBit ? ((mark[d] & checkBit) != 0) : (d == last);
        if (hit) {
            int s = src[i];
            int p = atomicAdd(eCnt, 1);
            if (p < Ecap) Elist[p] = make_int2(s, d);
            if (!(atomicOr(&mark[s], setBit) & setBit)) {
                int q = atomicAdd(fCnt, 1);
                if (q < Fcap) Flist[q] = s;
            }
        }
    }
}

__global__ void k_degm(const int* __restrict__ dst, const int* __restrict__ mark,
                       int* __restrict__ deg, int E) {
    int i = blockIdx.x * blockDim.x + threadIdx.x;
    if (i < E) {
        int d = dst[i];
        if (mark[d]) atomicAdd(&deg[d], 1);
    }
}

__global__ void k_dinvm(const int* __restrict__ mark, const int* __restrict__ deg,
                        float* __restrict__ dinv, int n) {
    int i = blockIdx.x * blockDim.x + threadIdx.x;
    if (i < n && mark[i]) dinv[i] = rsqrtf(1.0f + (float)deg[i]);
}

__global__ __launch_bounds__(256) void k_gemm_rows(
    const int* __restrict__ list, const int* __restrict__ cntPtr, int cap,
    const float* __restrict__ Xin, const float* __restrict__ bias,
    const float* __restrict__ W, const float* __restrict__ dinv,
    const int* __restrict__ mark, int aggBit, int last,
    float* __restrict__ H, float* __restrict__ AGG)
{
    __shared__ float wsm[128][128];
    const int t = threadIdx.x;

    {
        const float4* W4 = (const float4*)W;
        float4* S4 = (float4*)&wsm[0][0];
        #pragma unroll
        for (int it = 0; it < 16; ++it) S4[it * 256 + t] = W4[it * 256 + t];
    }
    __syncthreads();

    int cnt = *cntPtr; if (cnt > cap) cnt = cap;
    const int wave = t >> 6, lane = t & 63;

    for (int base = blockIdx.x * 4; base < cnt; base += gridDim.x * 4) {
        int r = base + wave;
        if (r >= cnt) continue;
        int v = list[r];
        size_t off = (size_t)v * NF;

        float x0, x1;
        if (bias) {
            x0 = fmaxf(Xin[off + lane]      + bias[lane],      0.f);
            x1 = fmaxf(Xin[off + lane + 64] + bias[lane + 64], 0.f);
        } else {
            x0 = Xin[off + lane];
            x1 = Xin[off + lane + 64];
        }

        float a0 = 0.f, a1 = 0.f;
        #pragma unroll 16
        for (int k = 0; k < 64; ++k) {
            float xk = __shfl(x0, k);
            a0 += xk * wsm[k][lane];
            a1 += xk * wsm[k][lane + 64];
        }
        #pragma unroll 16
        for (int k = 0; k < 64; ++k) {
            float xk = __shfl(x1, k);
            a0 += xk * wsm[k + 64][lane];
            a1 += xk * wsm[k + 64][lane + 64];
        }

        H[off + lane]      = a0;
        H[off + lane + 64] = a1;

        bool doAgg = (mark ? ((mark[v] & aggBit) != 0) : false) || (v == last);
        if (doAgg) {
            float di = dinv[v], s2 = di * di;
            AGG[off + lane]      = a0 * s2;
            AGG[off + lane + 64] = a1 * s2;
        }
    }
}

__global__ void k_scat(const int2* __restrict__ list, const int* __restrict__ cntPtr, int cap,
                       const float* __restrict__ dinv, const float* __restrict__ H,
                       float* __restrict__ AGG)
{
    int cnt = *cntPtr; if (cnt > cap) cnt = cap;
    int t = threadIdx.x;
    for (int i = blockIdx.x; i < cnt; i += gridDim.x) {
        int2 e = list[i];
        float w = dinv[e.x] * dinv[e.y];
        atomicAdd(&AGG[(size_t)e.y * NF + t], H[(size_t)e.x * NF + t] * w);
    }
}

__global__ void k_fc(const float* __restrict__ AGG3, const float* __restrict__ b3,
                     const float* __restrict__ fcW, const float* __restrict__ fcb,
                     float* __restrict__ out, int last)
{
    __shared__ float xrow[NF];
    int j = threadIdx.x;
    size_t off = (size_t)last * NF;
    xrow[j]      = fmaxf(AGG3[off + j]      + b3[j],      0.f);
    xrow[j + 64] = fmaxf(AGG3[off + j + 64] + b3[j + 64], 0.f);
    __syncthreads();
    float acc = fcb[j];
    #pragma unroll 16
    for (int k = 0; k < NF; ++k) acc += xrow[k] * fcW[k * OUTF + j];
    out[j] = acc;
}

// ---------------------------------------------------------------------------

extern "C" void kernel_launch(void* const* d_in, const int* in_sizes, int n_in,
                              void* d_out, int out_size, void* d_ws, size_t ws_size,
                              hipStream_t stream)
{
    const float* x    = (const float*)d_in[0];
    const int*   ei   = (const int*)d_in[1];
    const float* W1   = (const float*)d_in[2];
    const float* b1   = (const float*)d_in[3];
    const float* W2   = (const float*)d_in[4];
    const float* b2   = (const float*)d_in[5];
    const float* W3   = (const float*)d_in[6];
    const float* b3   = (const float*)d_in[7];
    const float* fcW  = (const float*)d_in[8];
    const float* fcb  = (const float*)d_in[9];
    float* out = (float*)d_out;

    const int n = in_sizes[0] / NF;       // 50000
    const int E = in_sizes[1] / 2;        // 600000
    const int* src = ei;
    const int* dst = ei + E;
    const int last = n - 1;

    char* wp = (char*)d_ws;
    auto alloc = [&](size_t bytes) -> void* {
        void* r = (void*)wp;
        wp += (bytes + 255) & ~(size_t)255;
        return r;
    };
    // zeroed region: deg | mark | cnt+barriers  (one memset)
    int*   deg  = (int*)alloc((size_t)n * 4);
    int*   mark = (int*)alloc((size_t)n * 4);
    int*   cnt  = (int*)alloc(256 * 4);       // cnt[0..5] counters; cnt[64+] barrier slots
    size_t zbytes = (char*)wp - (char*)deg;

    float* dinv = (float*)alloc((size_t)n * 4);      // fallback path only
    int*   F2   = (int*) alloc(CAP_F2 * 4);
    int2*  E3   = (int2*)alloc(CAP_E3 * 8);
    int*   F1   = (int*) alloc(CAP_F1 * 4);
    int2*  E2   = (int2*)alloc(CAP_E2 * 8);
    int*   F0   = (int*) alloc(CAP_F0 * 4);
    int2*  E1   = (int2*)alloc(CAP_E1 * 8);
    float* H    = (float*)alloc((size_t)n * NF * 4);
    float* aggA = (float*)alloc((size_t)n * NF * 4);
    float* aggB = (float*)alloc((size_t)n * NF * 4);

    // ---- try the single cooperative kernel with hand-rolled barriers ----
    static int coopState = -2;   // -2 untested, -1 unsupported, >0 grid size
    if (coopState != -1) {
        if (coopState == -2) {
            int perCU = 0;
            if (hipOccupancyMaxActiveBlocksPerMultiprocessor(&perCU, k_fused, 256, 0)
                    != hipSuccess || perCU < 1)
                perCU = 1;
            long g = (long)perCU * 256;   // 256 CUs on MI355X
            if (g > 512) g = 512;         // 64KB LDS -> 2 blocks/CU max
            coopState = (int)g;
        }
        KArgs ha;
        ha.x = x; ha.srcp = src; ha.dstp = dst;
        ha.E = E; ha.n = n; ha.last = last;
        ha.W1 = W1; ha.b1 = b1; ha.W2 = W2; ha.b2 = b2;
        ha.W3 = W3; ha.b3 = b3; ha.fcW = fcW; ha.fcb = fcb;
        ha.deg = deg; ha.mark = mark; ha.cnt = cnt; ha.bar = cnt + 64;
        ha.F2 = F2; ha.E3l = E3; ha.F1 = F1; ha.E2l = E2; ha.F0 = F0; ha.E1l = E1;
        ha.H = H; ha.aggA = aggA; ha.aggB = aggB; ha.out = out;

        hipMemsetAsync(deg, 0, zbytes, stream);   // zeros deg, mark, cnt, barriers
        void* params[1] = { (void*)&ha };
        hipError_t err = hipLaunchCooperativeKernel(k_fused, dim3(coopState), dim3(256),
                                                    params, 0u, stream);
        if (err == hipSuccess) return;
        coopState = -1;          // coop not available; use fallback
        (void)hipGetLastError();
    }

    // ---- fallback: original multi-kernel pipeline ----
    const int B  = 256;
    const int EB = (E + B - 1) / B;
    const int NB = (n + B - 1) / B;

    hipMemsetAsync(deg, 0, zbytes, stream);
    k_seed<<<1, 64, 0, stream>>>(mark, F2, cnt, last);

    k_mark<<<EB, B, 0, stream>>>(src, dst, E, mark, 0,  M2, last,
                                 E3, CAP_E3, &cnt[1], F2, CAP_F2, &cnt[0],
                                 nullptr, nullptr, 0);
    k_mark<<<EB, B, 0, stream>>>(src, dst, E, mark, M2, M1, last,
                                 E2, CAP_E2, &cnt[3], F1, CAP_F1, &cnt[2],
                                 F2, &cnt[0], CAP_F2);
    k_mark<<<EB, B, 0, stream>>>(src, dst, E, mark, M1, M0, last,
                                 E1, CAP_E1, &cnt[5], F0, CAP_F0, &cnt[4],
                                 F1, &cnt[2], CAP_F1);

    k_degm <<<EB, B, 0, stream>>>(dst, mark, deg, E);
    k_dinvm<<<NB, B, 0, stream>>>(mark, deg, dinv, n);

    k_gemm_rows<<<384, B, 0, stream>>>(F0, &cnt[4], CAP_F0, x, nullptr, W1,
                                       dinv, mark, M1, -1, H, aggA);
    k_scat<<<2048, 128, 0, stream>>>(E1, &cnt[5], CAP_E1, dinv, H, aggA);

    k_gemm_rows<<<384, B, 0, stream>>>(F1, &cnt[2], CAP_F1, aggA, b1, W2,
                                       dinv, mark, M2, -1, H, aggB);
    k_scat<<<2048, 128, 0, stream>>>(E2, &cnt[3], CAP_E2, dinv, H, aggB);

    k_gemm_rows<<<384, B, 0, stream>>>(F2, &cnt[0], CAP_F2, aggB, b2, W3,
                                       dinv, nullptr, 0, last, H, aggA);
    k_scat<<<2048, 128, 0, stream>>>(E3, &cnt[1], CAP_E3, dinv, H, aggA);

    k_fc<<<1, 64, 0, stream>>>(aggA, b3, fcW, fcb, out, last);
}

// Round 4
// 347.932 us; speedup vs baseline: 1.7918x; 1.5247x over previous
//
#include <hip/hip_runtime.h>

#define NF 128
#define OUTF 64

// mark bits
#define M2 1   // layer-2 gather frontier (in-neighbors of last, + last)
#define M1 2   // layer-1 gather frontier
#define M0 4   // rows for GEMM1

// capacity caps (expected ~13 / ~180 / ~2600 nodes; huge slack)
#define CAP_F2 2048
#define CAP_E3 4096
#define CAP_F1 32768
#define CAP_E2 65536
#define CAP_F0 131072
#define CAP_E1 262144

// cnt[0]=F2, cnt[1]=E3, cnt[2]=F1, cnt[3]=E2, cnt[4]=F0, cnt[5]=E1
// bar = cnt+64: per-barrier block of 1024 ints:
//   leaf g at [b*1024 + g*16], root at [b*1024+512], flag at [b*1024+528]

struct KArgs {
    const float* x;
    const int* srcp;
    const int* dstp;
    int E, n, last;
    const float* W1; const float* b1;
    const float* W2; const float* b2;
    const float* W3; const float* b3;
    const float* fcW; const float* fcb;
    int* deg; int* mark; int* cnt; int* bar;
    int* F2; int2* E3l; int* F1; int2* E2l; int* F0; int2* E1l;
    float* H; float* aggA; float* aggB;
    float* out;
};

// ---- two-level grid barrier: 32 leaf lines + root + separate release flag ----
__device__ __forceinline__ void gbar(int* base) {
    __syncthreads();
    if (threadIdx.x == 0) {
        __threadfence();                          // release (L2 writeback)
        const int nb = (int)gridDim.x;
        const int g = blockIdx.x >> 4;            // 16 blocks per leaf
        int* leaf = base + g * 16;
        int* root = base + 512;
        int* flag = base + 528;
        int leafSize = nb - (g << 4); if (leafSize > 16) leafSize = 16;
        if (atomicAdd(leaf, 1) == leafSize - 1) {
            int nleaf = (nb + 15) >> 4;
            if (atomicAdd(root, 1) == nleaf - 1) {
                __hip_atomic_store(flag, 1, __ATOMIC_RELAXED,
                                   __HIP_MEMORY_SCOPE_AGENT);
            }
        }
        while (__hip_atomic_load(flag, __ATOMIC_RELAXED,
                                 __HIP_MEMORY_SCOPE_AGENT) == 0) {
            __builtin_amdgcn_s_sleep(2);          // constant immediate (s_sleep imm)
        }
        __threadfence();                          // acquire (L1/L2 invalidate)
    }
    __syncthreads();
}

// ---- row-list GEMM, W staged in LDS; pure H = row @ W (no AGG/deg) ----
__device__ __forceinline__ void gemm_rows_lds(
    const int* __restrict__ list, int rows,
    const float* __restrict__ Xin, const float* __restrict__ bias,
    const float* __restrict__ W, float* __restrict__ H,
    float (&wsm)[128][128])
{
    const bool active = ((int)blockIdx.x * 4 < rows);   // block-uniform
    if (!active) return;
    const int t = threadIdx.x;
    {
        const float4* W4 = (const float4*)W;
        float4* S4 = (float4*)&wsm[0][0];
        #pragma unroll
        for (int it = 0; it < 16; ++it) S4[it * 256 + t] = W4[it * 256 + t];
    }
    __syncthreads();
    const int wave = t >> 6, lane = t & 63;
    for (int base = blockIdx.x * 4; base < rows; base += gridDim.x * 4) {
        int r = base + wave;
        if (r >= rows) continue;
        int v = list[r];
        size_t off = (size_t)v * NF;

        float x0, x1;
        if (bias) {
            x0 = fmaxf(Xin[off + lane]      + bias[lane],      0.f);
            x1 = fmaxf(Xin[off + lane + 64] + bias[lane + 64], 0.f);
        } else {
            x0 = Xin[off + lane];
            x1 = Xin[off + lane + 64];
        }

        float a0 = 0.f, a1 = 0.f;
        #pragma unroll 16
        for (int k = 0; k < 64; ++k) {
            float xk = __shfl(x0, k);
            a0 += xk * wsm[k][lane];
            a1 += xk * wsm[k][lane + 64];
        }
        #pragma unroll 16
        for (int k = 0; k < 64; ++k) {
            float xk = __shfl(x1, k);
            a0 += xk * wsm[k + 64][lane];
            a1 += xk * wsm[k + 64][lane + 64];
        }

        H[off + lane]      = a0;
        H[off + lane + 64] = a1;
    }
}

// ---- per-edge hit handlers (rare paths) ----
__device__ __forceinline__ void p1_hit(const KArgs& a, int d, int i) {
    if (d == a.last) {
        int s = a.srcp[i];
        int p = atomicAdd(&a.cnt[1], 1);
        if (p < CAP_E3) a.E3l[p] = make_int2(s, d);
        if (!(atomicOr(&a.mark[s], M2) & M2)) {
            int q = atomicAdd(&a.cnt[0], 1);
            if (q < CAP_F2) a.F2[q] = s;
            int r = atomicAdd(&a.cnt[3], 1);           // self-edge into E2
            if (r < CAP_E2) a.E2l[r] = make_int2(s, s);
        }
    }
}

__device__ __forceinline__ void p2_hit(const KArgs& a, int d, int i) {
    if (a.mark[d] & M2) {
        int s = a.srcp[i];
        int p = atomicAdd(&a.cnt[3], 1);
        if (p < CAP_E2) a.E2l[p] = make_int2(s, d);
        if (!(atomicOr(&a.mark[s], M1) & M1)) {
            int q = atomicAdd(&a.cnt[2], 1);
            if (q < CAP_F1) a.F1[q] = s;
            int r = atomicAdd(&a.cnt[5], 1);           // self-edge into E1
            if (r < CAP_E1) a.E1l[r] = make_int2(s, s);
        }
    }
}

__device__ __forceinline__ void p3_hit(const KArgs& a, int d, int i) {
    if (a.mark[d] & M1) {
        int s = a.srcp[i];
        int p = atomicAdd(&a.cnt[5], 1);
        if (p < CAP_E1) a.E1l[p] = make_int2(s, d);
        if (!(atomicOr(&a.mark[s], M0) & M0)) {
            int q = atomicAdd(&a.cnt[4], 1);
            if (q < CAP_F0) a.F0[q] = s;
        }
    }
}

__global__ __launch_bounds__(256, 2) void k_fused(KArgs a)
{
    __shared__ float wsm[128][128];   // 64 KB: W staging; reused by tail
    const int gtid = blockIdx.x * blockDim.x + threadIdx.x;
    const int gstride = gridDim.x * blockDim.x;
    const int E = a.E;
    int* bar = a.bar;
    const bool vec4 = (((uintptr_t)a.dstp & 15) == 0);
    const int4* d4p = (const int4*)a.dstp;
    const int nq = E >> 2;

    // ---- P1: seed + level-1 scan (dst == last). NO deg atomics here. ----
    if (gtid == 0) {
        if (!(atomicOr(&a.mark[a.last], M2) & M2)) {
            int p = atomicAdd(&a.cnt[0], 1);
            if (p < CAP_F2) a.F2[p] = a.last;
            int r = atomicAdd(&a.cnt[3], 1);           // self-edge last in E2
            if (r < CAP_E2) a.E2l[r] = make_int2(a.last, a.last);
            int e = atomicAdd(&a.cnt[1], 1);           // self-edge last in E3
            if (e < CAP_E3) a.E3l[e] = make_int2(a.last, a.last);
        }
    }
    if (vec4) {
        for (int q = gtid; q < nq; q += gstride) {
            int4 d4 = d4p[q];
            int i = q << 2;
            p1_hit(a, d4.x, i); p1_hit(a, d4.y, i + 1);
            p1_hit(a, d4.z, i + 2); p1_hit(a, d4.w, i + 3);
        }
        for (int i = (nq << 2) + gtid; i < E; i += gstride) p1_hit(a, a.dstp[i], i);
    } else {
        for (int i = gtid; i < E; i += gstride) p1_hit(a, a.dstp[i], i);
    }
    gbar(&bar[0]);

    // ---- P2: level-2 scan (M2 -> M1) + self-prop F2 into F1 (+E1 self) ----
    {
        int sc = min(a.cnt[0], CAP_F2);
        for (int i = gtid; i < sc; i += gstride) {
            int v = a.F2[i];
            if (!(atomicOr(&a.mark[v], M1) & M1)) {
                int p = atomicAdd(&a.cnt[2], 1);
                if (p < CAP_F1) a.F1[p] = v;
                int r = atomicAdd(&a.cnt[5], 1);
                if (r < CAP_E1) a.E1l[r] = make_int2(v, v);
            }
        }
        if (vec4) {
            for (int q = gtid; q < nq; q += gstride) {
                int4 d4 = d4p[q];
                int i = q << 2;
                p2_hit(a, d4.x, i); p2_hit(a, d4.y, i + 1);
                p2_hit(a, d4.z, i + 2); p2_hit(a, d4.w, i + 3);
            }
            for (int i = (nq << 2) + gtid; i < E; i += gstride) p2_hit(a, a.dstp[i], i);
        } else {
            for (int i = gtid; i < E; i += gstride) p2_hit(a, a.dstp[i], i);
        }
    }
    gbar(&bar[1024]);

    // ---- P3: level-3 scan (M1 -> M0) + self-prop F1 into F0 ----
    {
        int sc = min(a.cnt[2], CAP_F1);
        for (int i = gtid; i < sc; i += gstride) {
            int v = a.F1[i];
            if (!(atomicOr(&a.mark[v], M0) & M0)) {
                int p = atomicAdd(&a.cnt[4], 1);
                if (p < CAP_F0) a.F0[p] = v;
            }
        }
        if (vec4) {
            for (int q = gtid; q < nq; q += gstride) {
                int4 d4 = d4p[q];
                int i = q << 2;
                p3_hit(a, d4.x, i); p3_hit(a, d4.y, i + 1);
                p3_hit(a, d4.z, i + 2); p3_hit(a, d4.w, i + 3);
            }
            for (int i = (nq << 2) + gtid; i < E; i += gstride) p3_hit(a, a.dstp[i], i);
        } else {
            for (int i = gtid; i < E; i += gstride) p3_hit(a, a.dstp[i], i);
        }
    }
    gbar(&bar[2048]);

    // ---- P4: conditional deg scan + AGG zero-init + GEMM1 (W1 in LDS) ----
    {
        // a) in-degree for marked nodes only (~5.6% hit rate, ~34K atomics)
        if (vec4) {
            for (int q = gtid; q < nq; q += gstride) {
                int4 d4 = d4p[q];
                if (a.mark[d4.x]) atomicAdd(&a.deg[d4.x], 1);
                if (a.mark[d4.y]) atomicAdd(&a.deg[d4.y], 1);
                if (a.mark[d4.z]) atomicAdd(&a.deg[d4.z], 1);
                if (a.mark[d4.w]) atomicAdd(&a.deg[d4.w], 1);
            }
            for (int i = (nq << 2) + gtid; i < E; i += gstride) {
                int d = a.dstp[i];
                if (a.mark[d]) atomicAdd(&a.deg[d], 1);
            }
        } else {
            for (int i = gtid; i < E; i += gstride) {
                int d = a.dstp[i];
                if (a.mark[d]) atomicAdd(&a.deg[d], 1);
            }
        }
        // b) zero aggA rows of F1, aggB rows of F2 (tiny)
        int f1 = min(a.cnt[2], CAP_F1);
        for (int i = gtid; i < f1 * NF; i += gstride)
            a.aggA[(size_t)a.F1[i >> 7] * NF + (i & 127)] = 0.f;
        int f2 = min(a.cnt[0], CAP_F2);
        for (int i = gtid; i < f2 * NF; i += gstride)
            a.aggB[(size_t)a.F2[i >> 7] * NF + (i & 127)] = 0.f;
        // c) H1 = x @ W1 on F0 rows
        gemm_rows_lds(a.F0, min(a.cnt[4], CAP_F0), a.x, nullptr, a.W1, a.H, wsm);
    }
    gbar(&bar[3072]);

    // ---- P5: scatter E1 into aggA (self-edges included) ----
    {
        int ecnt = min(a.cnt[5], CAP_E1);
        int grp = gtid >> 7, f = gtid & 127, ngrp = gstride >> 7;
        for (int i = grp; i < ecnt; i += ngrp) {
            int2 e = a.E1l[i];
            float w = rsqrtf(1.f + (float)a.deg[e.x]) * rsqrtf(1.f + (float)a.deg[e.y]);
            atomicAdd(&a.aggA[(size_t)e.y * NF + f], a.H[(size_t)e.x * NF + f] * w);
        }
    }
    gbar(&bar[4096]);

    // ---- P6: GEMM2 on F1 rows: H2 = relu(aggA+b1) @ W2 (W2 in LDS) ----
    gemm_rows_lds(a.F1, min(a.cnt[2], CAP_F1), a.aggA, a.b1, a.W2, a.H, wsm);
    gbar(&bar[5120]);

    // ---- P7 (block 0 only): scatter E2 + GEMM3 + E3 reduce + FC ----
    if (blockIdx.x == 0) {
        const int t = threadIdx.x;
        // a) scatter E2 into aggB (~180 edges; 2 groups of 128 threads)
        {
            int ecnt = min(a.cnt[3], CAP_E2);
            int grp = t >> 7, f = t & 127;
            for (int i = grp; i < ecnt; i += 2) {
                int2 e = a.E2l[i];
                float w = rsqrtf(1.f + (float)a.deg[e.x]) * rsqrtf(1.f + (float)a.deg[e.y]);
                atomicAdd(&a.aggB[(size_t)e.y * NF + f], a.H[(size_t)e.x * NF + f] * w);
            }
        }
        __threadfence();     // atomics updated L2 only; invalidate L1 before re-reads
        __syncthreads();
        // b) stage W3 into LDS
        {
            const float4* W4 = (const float4*)a.W3;
            float4* S4 = (float4*)&wsm[0][0];
            #pragma unroll
            for (int it = 0; it < 16; ++it) S4[it * 256 + t] = W4[it * 256 + t];
        }
        __syncthreads();
        // c) GEMM3 on F2 rows: H3 = relu(aggB+b2) @ W3
        const int wave = t >> 6, lane = t & 63;
        int rows = min(a.cnt[0], CAP_F2);
        for (int r = wave; r < rows; r += 4) {
            int v = a.F2[r];
            size_t off = (size_t)v * NF;
            float x0 = fmaxf(a.aggB[off + lane]      + a.b2[lane],      0.f);
            float x1 = fmaxf(a.aggB[off + lane + 64] + a.b2[lane + 64], 0.f);
            float a0 = 0.f, a1 = 0.f;
            #pragma unroll 16
            for (int k = 0; k < 64; ++k) {
                float xk = __shfl(x0, k);
                a0 += xk * wsm[k][lane];
                a1 += xk * wsm[k][lane + 64];
            }
            #pragma unroll 16
            for (int k = 0; k < 64; ++k) {
                float xk = __shfl(x1, k);
                a0 += xk * wsm[k + 64][lane];
                a1 += xk * wsm[k + 64][lane + 64];
            }
            a.H[off + lane]      = a0;
            a.H[off + lane + 64] = a1;
        }
        __syncthreads();
        // d) E3 register-reduce (self-edge included) + relu + bias
        if (t < NF) {
            float dl = rsqrtf(1.f + (float)a.deg[a.last]);
            float acc = 0.f;
            int e3 = min(a.cnt[1], CAP_E3);
            for (int i = 0; i < e3; ++i) {
                int s = a.E3l[i].x;
                acc += rsqrtf(1.f + (float)a.deg[s]) * dl * a.H[(size_t)s * NF + t];
            }
            wsm[0][t] = fmaxf(acc + a.b3[t], 0.f);
        }
        __syncthreads();
        // e) FC
        if (t < OUTF) {
            float acc = a.fcb[t];
            #pragma unroll 16
            for (int k = 0; k < NF; ++k) acc += wsm[0][k] * a.fcW[k * OUTF + t];
            a.out[t] = acc;
        }
    }
}

// ---------------------------------------------------------------------------
// Fallback: proven multi-kernel pipeline (used only if coop launch rejected)
// ---------------------------------------------------------------------------

__global__ void k_seed(int* __restrict__ mark, int* __restrict__ F2,
                       int* __restrict__ cnt, int last) {
    if (threadIdx.x == 0) {
        mark[last] = M2;
        F2[0] = last;
        cnt[0] = 1;
    }
}

__global__ void k_mark(const int* __restrict__ src, const int* __restrict__ dst, int E,
                       int* __restrict__ mark, int checkBit, int setBit, int last,
                       int2* __restrict__ Elist, int Ecap, int* __restrict__ eCnt,
                       int* __restrict__ Flist, int Fcap, int* __restrict__ fCnt,
                       const int* __restrict__ selfList, const int* __restrict__ selfCnt,
                       int selfCap)
{
    int i = blockIdx.x * blockDim.x + threadIdx.x;

    if (selfList) {
        int sc = *selfCnt; if (sc > selfCap) sc = selfCap;
        if (i < sc) {
            int v = selfList[i];
            if (!(atomicOr(&mark[v], setBit) & setBit)) {
                int p = atomicAdd(fCnt, 1);
                if (p < Fcap) Flist[p] = v;
            }
        }
    }
    if (i < E) {
        int d = dst[i];
        bool hit = checkBit ? ((mark[d] & checkBit) != 0) : (d == last);
        if (hit) {
            int s = src[i];
            int p = atomicAdd(eCnt, 1);
            if (p < Ecap) Elist[p] = make_int2(s, d);
            if (!(atomicOr(&mark[s], setBit) & setBit)) {
                int q = atomicAdd(fCnt, 1);
                if (q < Fcap) Flist[q] = s;
            }
        }
    }
}

__global__ void k_degm(const int* __restrict__ dst, const int* __restrict__ mark,
                       int* __restrict__ deg, int E) {
    int i = blockIdx.x * blockDim.x + threadIdx.x;
    if (i < E) {
        int d = dst[i];
        if (mark[d]) atomicAdd(&deg[d], 1);
    }
}

__global__ void k_dinvm(const int* __restrict__ mark, const int* __restrict__ deg,
                        float* __restrict__ dinv, int n) {
    int i = blockIdx.x * blockDim.x + threadIdx.x;
    if (i < n && mark[i]) dinv[i] = rsqrtf(1.0f + (float)deg[i]);
}

__global__ __launch_bounds__(256) void k_gemm_rows(
    const int* __restrict__ list, const int* __restrict__ cntPtr, int cap,
    const float* __restrict__ Xin, const float* __restrict__ bias,
    const float* __restrict__ W, const float* __restrict__ dinv,
    const int* __restrict__ mark, int aggBit, int last,
    float* __restrict__ H, float* __restrict__ AGG)
{
    __shared__ float wsm[128][128];
    const int t = threadIdx.x;

    {
        const float4* W4 = (const float4*)W;
        float4* S4 = (float4*)&wsm[0][0];
        #pragma unroll
        for (int it = 0; it < 16; ++it) S4[it * 256 + t] = W4[it * 256 + t];
    }
    __syncthreads();

    int cnt = *cntPtr; if (cnt > cap) cnt = cap;
    const int wave = t >> 6, lane = t & 63;

    for (int base = blockIdx.x * 4; base < cnt; base += gridDim.x * 4) {
        int r = base + wave;
        if (r >= cnt) continue;
        int v = list[r];
        size_t off = (size_t)v * NF;

        float x0, x1;
        if (bias) {
            x0 = fmaxf(Xin[off + lane]      + bias[lane],      0.f);
            x1 = fmaxf(Xin[off + lane + 64] + bias[lane + 64], 0.f);
        } else {
            x0 = Xin[off + lane];
            x1 = Xin[off + lane + 64];
        }

        float a0 = 0.f, a1 = 0.f;
        #pragma unroll 16
        for (int k = 0; k < 64; ++k) {
            float xk = __shfl(x0, k);
            a0 += xk * wsm[k][lane];
            a1 += xk * wsm[k][lane + 64];
        }
        #pragma unroll 16
        for (int k = 0; k < 64; ++k) {
            float xk = __shfl(x1, k);
            a0 += xk * wsm[k + 64][lane];
            a1 += xk * wsm[k + 64][lane + 64];
        }

        H[off + lane]      = a0;
        H[off + lane + 64] = a1;

        bool doAgg = (mark ? ((mark[v] & aggBit) != 0) : false) || (v == last);
        if (doAgg) {
            float di = dinv[v], s2 = di * di;
            AGG[off + lane]      = a0 * s2;
            AGG[off + lane + 64] = a1 * s2;
        }
    }
}

__global__ void k_scat(const int2* __restrict__ list, const int* __restrict__ cntPtr, int cap,
                       const float* __restrict__ dinv, const float* __restrict__ H,
                       float* __restrict__ AGG)
{
    int cnt = *cntPtr; if (cnt > cap) cnt = cap;
    int t = threadIdx.x;
    for (int i = blockIdx.x; i < cnt; i += gridDim.x) {
        int2 e = list[i];
        float w = dinv[e.x] * dinv[e.y];
        atomicAdd(&AGG[(size_t)e.y * NF + t], H[(size_t)e.x * NF + t] * w);
    }
}

__global__ void k_fc(const float* __restrict__ AGG3, const float* __restrict__ b3,
                     const float* __restrict__ fcW, const float* __restrict__ fcb,
                     float* __restrict__ out, int last)
{
    __shared__ float xrow[NF];
    int j = threadIdx.x;
    size_t off = (size_t)last * NF;
    xrow[j]      = fmaxf(AGG3[off + j]      + b3[j],      0.f);
    xrow[j + 64] = fmaxf(AGG3[off + j + 64] + b3[j + 64], 0.f);
    __syncthreads();
    float acc = fcb[j];
    #pragma unroll 16
    for (int k = 0; k < NF; ++k) acc += xrow[k] * fcW[k * OUTF + j];
    out[j] = acc;
}

// ---------------------------------------------------------------------------

extern "C" void kernel_launch(void* const* d_in, const int* in_sizes, int n_in,
                              void* d_out, int out_size, void* d_ws, size_t ws_size,
                              hipStream_t stream)
{
    const float* x    = (const float*)d_in[0];
    const int*   ei   = (const int*)d_in[1];
    const float* W1   = (const float*)d_in[2];
    const float* b1   = (const float*)d_in[3];
    const float* W2   = (const float*)d_in[4];
    const float* b2   = (const float*)d_in[5];
    const float* W3   = (const float*)d_in[6];
    const float* b3   = (const float*)d_in[7];
    const float* fcW  = (const float*)d_in[8];
    const float* fcb  = (const float*)d_in[9];
    float* out = (float*)d_out;

    const int n = in_sizes[0] / NF;       // 50000
    const int E = in_sizes[1] / 2;        // 600000
    const int* src = ei;
    const int* dst = ei + E;
    const int last = n - 1;

    char* wp = (char*)d_ws;
    auto alloc = [&](size_t bytes) -> void* {
        void* r = (void*)wp;
        wp += (bytes + 255) & ~(size_t)255;
        return r;
    };
    // zeroed region: deg | mark | cnt+barriers  (one memset)
    int*   deg  = (int*)alloc((size_t)n * 4);
    int*   mark = (int*)alloc((size_t)n * 4);
    int*   cnt  = (int*)alloc((64 + 8 * 1024) * 4);   // counters + 8 barrier blocks
    size_t zbytes = (char*)wp - (char*)deg;

    float* dinv = (float*)alloc((size_t)n * 4);      // fallback path only
    int*   F2   = (int*) alloc(CAP_F2 * 4);
    int2*  E3   = (int2*)alloc(CAP_E3 * 8);
    int*   F1   = (int*) alloc(CAP_F1 * 4);
    int2*  E2   = (int2*)alloc(CAP_E2 * 8);
    int*   F0   = (int*) alloc(CAP_F0 * 4);
    int2*  E1   = (int2*)alloc(CAP_E1 * 8);
    float* H    = (float*)alloc((size_t)n * NF * 4);
    float* aggA = (float*)alloc((size_t)n * NF * 4);
    float* aggB = (float*)alloc((size_t)n * NF * 4);

    // ---- single fused kernel (cooperative launch for co-residency) ----
    static int coopState = -2;   // -2 untested, -1 unsupported, >0 grid size
    if (coopState != -1) {
        if (coopState == -2) {
            int perCU = 0;
            if (hipOccupancyMaxActiveBlocksPerMultiprocessor(&perCU, k_fused, 256, 0)
                    != hipSuccess || perCU < 1)
                perCU = 1;
            long g = (long)perCU * 256;   // 256 CUs on MI355X
            if (g > 512) g = 512;         // 64KB LDS -> 2 blocks/CU max
            coopState = (int)g;
        }
        KArgs ha;
        ha.x = x; ha.srcp = src; ha.dstp = dst;
        ha.E = E; ha.n = n; ha.last = last;
        ha.W1 = W1; ha.b1 = b1; ha.W2 = W2; ha.b2 = b2;
        ha.W3 = W3; ha.b3 = b3; ha.fcW = fcW; ha.fcb = fcb;
        ha.deg = deg; ha.mark = mark; ha.cnt = cnt; ha.bar = cnt + 64;
        ha.F2 = F2; ha.E3l = E3; ha.F1 = F1; ha.E2l = E2; ha.F0 = F0; ha.E1l = E1;
        ha.H = H; ha.aggA = aggA; ha.aggB = aggB; ha.out = out;

        hipMemsetAsync(deg, 0, zbytes, stream);   // zeros deg, mark, cnt, barriers
        void* params[1] = { (void*)&ha };
        hipError_t err = hipLaunchCooperativeKernel(k_fused, dim3(coopState), dim3(256),
                                                    params, 0u, stream);
        if (err == hipSuccess) return;
        coopState = -1;          // coop not available; use fallback
        (void)hipGetLastError();
    }

    // ---- fallback: original multi-kernel pipeline ----
    const int B  = 256;
    const int EB = (E + B - 1) / B;
    const int NB = (n + B - 1) / B;

    hipMemsetAsync(deg, 0, zbytes, stream);
    k_seed<<<1, 64, 0, stream>>>(mark, F2, cnt, last);

    k_mark<<<EB, B, 0, stream>>>(src, dst, E, mark, 0,  M2, last,
                                 E3, CAP_E3, &cnt[1], F2, CAP_F2, &cnt[0],
                                 nullptr, nullptr, 0);
    k_mark<<<EB, B, 0, stream>>>(src, dst, E, mark, M2, M1, last,
                                 E2, CAP_E2, &cnt[3], F1, CAP_F1, &cnt[2],
                                 F2, &cnt[0], CAP_F2);
    k_mark<<<EB, B, 0, stream>>>(src, dst, E, mark, M1, M0, last,
                                 E1, CAP_E1, &cnt[5], F0, CAP_F0, &cnt[4],
                                 F1, &cnt[2], CAP_F1);

    k_degm <<<EB, B, 0, stream>>>(dst, mark, deg, E);
    k_dinvm<<<NB, B, 0, stream>>>(mark, deg, dinv, n);

    k_gemm_rows<<<384, B, 0, stream>>>(F0, &cnt[4], CAP_F0, x, nullptr, W1,
                                       dinv, mark, M1, -1, H, aggA);
    k_scat<<<2048, 128, 0, stream>>>(E1, &cnt[5], CAP_E1, dinv, H, aggA);

    k_gemm_rows<<<384, B, 0, stream>>>(F1, &cnt[2], CAP_F1, aggA, b1, W2,
                                       dinv, mark, M2, -1, H, aggB);
    k_scat<<<2048, 128, 0, stream>>>(E2, &cnt[3], CAP_E2, dinv, H, aggB);

    k_gemm_rows<<<384, B, 0, stream>>>(F2, &cnt[0], CAP_F2, aggB, b2, W3,
                                       dinv, nullptr, 0, last, H, aggA);
    k_scat<<<2048, 128, 0, stream>>>(E3, &cnt[1], CAP_E3, dinv, H, aggA);

    k_fc<<<1, 64, 0, stream>>>(aggA, b3, fcW, fcb, out, last);
}

// Round 5
// 224.340 us; speedup vs baseline: 2.7789x; 1.5509x over previous
//
#include <hip/hip_runtime.h>

#define NF 128
#define OUTF 64

// mark bits
#define M2 1
#define M1 2
#define M0 4

// capacity caps (expected ~13 / ~180 / ~2600 nodes; huge slack)
#define CAP_F2 2048
#define CAP_E3 4096
#define CAP_F1 32768
#define CAP_E2 65536
#define CAP_F0 131072
#define CAP_E1 262144

// cnt[0]=F2, cnt[1]=E3, cnt[2]=F1, cnt[3]=E2, cnt[4]=F0, cnt[5]=E1
// bar = cnt+64: per-barrier block of 1024 ints:
//   leaf g at [b*1024+g*16], root [b*1024+512], flag [b*1024+528]

struct KArgs {
    const float* x;
    const int* srcp;
    const int* dstp;
    int E, n, last;
    const float* W1; const float* b1;
    const float* W2; const float* b2;
    const float* W3; const float* b3;
    const float* fcW; const float* fcb;
    int* deg; int* mark; int* cnt; int* bar;
    int* F2; int2* E3l; int* F1; int2* E2l; int* F0; int2* E1l;
    float* H; float* aggA; float* aggB;
    float* out;
};

// ---------- agent-scope (IF-coherent, L1/L2-bypass) access helpers ----------
__device__ __forceinline__ int ag_load_i(const int* p) {
    return __hip_atomic_load((int*)p, __ATOMIC_RELAXED, __HIP_MEMORY_SCOPE_AGENT);
}
__device__ __forceinline__ float ag_load_f(const float* p) {
    return __hip_atomic_load((float*)p, __ATOMIC_RELAXED, __HIP_MEMORY_SCOPE_AGENT);
}
__device__ __forceinline__ void ag_store_i(int* p, int v) {
    __hip_atomic_store(p, v, __ATOMIC_RELAXED, __HIP_MEMORY_SCOPE_AGENT);
}
__device__ __forceinline__ void ag_store_f(float* p, float v) {
    __hip_atomic_store(p, v, __ATOMIC_RELAXED, __HIP_MEMORY_SCOPE_AGENT);
}
__device__ __forceinline__ int2 ag_load_e(const int2* p) {
    unsigned long long v = __hip_atomic_load((unsigned long long*)p,
                                             __ATOMIC_RELAXED, __HIP_MEMORY_SCOPE_AGENT);
    int2 r; r.x = (int)(unsigned)(v & 0xffffffffull); r.y = (int)(unsigned)(v >> 32);
    return r;
}
__device__ __forceinline__ void ag_store_e(int2* p, int2 v) {
    unsigned long long u = ((unsigned long long)(unsigned)v.y << 32) | (unsigned)v.x;
    __hip_atomic_store((unsigned long long*)p, u, __ATOMIC_RELAXED,
                       __HIP_MEMORY_SCOPE_AGENT);
}

// ---- cache-maintenance-free grid barrier ----
// Sound because ALL mutable cross-block data moves via agent-scope (sc1) ops:
// nothing stale can sit in L1/L2, so no wbl2/inv needed at the barrier.
__device__ __forceinline__ void gbar(int* base) {
    __syncthreads();                              // drains each wave's vmcnt
    if (threadIdx.x == 0) {
        asm volatile("s_waitcnt vmcnt(0)" ::: "memory");
        const int nb = (int)gridDim.x;
        const int g = blockIdx.x >> 4;            // 16 blocks per leaf
        int* leaf = base + g * 16;
        int* root = base + 512;
        int* flag = base + 528;
        int leafSize = nb - (g << 4); if (leafSize > 16) leafSize = 16;
        if (__hip_atomic_fetch_add(leaf, 1, __ATOMIC_RELAXED,
                                   __HIP_MEMORY_SCOPE_AGENT) == leafSize - 1) {
            int nleaf = (nb + 15) >> 4;
            if (__hip_atomic_fetch_add(root, 1, __ATOMIC_RELAXED,
                                       __HIP_MEMORY_SCOPE_AGENT) == nleaf - 1) {
                __hip_atomic_store(flag, 1, __ATOMIC_RELEASE,
                                   __HIP_MEMORY_SCOPE_AGENT);   // single release
            }
        }
        while (__hip_atomic_load(flag, __ATOMIC_RELAXED,
                                 __HIP_MEMORY_SCOPE_AGENT) == 0) {
            __builtin_amdgcn_s_sleep(2);
        }
        asm volatile("" ::: "memory");            // compiler-only acquire fence
    }
    __syncthreads();
}

// ---- row-list GEMM, W staged in LDS; H written agent-scope ----
// AG_IN: input rows are workspace (agent loads) vs immutable input (cached)
template<bool AG_IN>
__device__ __forceinline__ void gemm_rows_lds(
    const int* __restrict__ list, int rows,
    const float* __restrict__ Xin, const float* __restrict__ bias,
    const float* __restrict__ W, float* __restrict__ H,
    float (&wsm)[128][128])
{
    const bool active = ((int)blockIdx.x * 4 < rows);   // block-uniform
    if (!active) return;                                // falls through to caller's gbar
    const int t = threadIdx.x;
    {
        const float4* W4 = (const float4*)W;
        float4* S4 = (float4*)&wsm[0][0];
        #pragma unroll
        for (int it = 0; it < 16; ++it) S4[it * 256 + t] = W4[it * 256 + t];
    }
    __syncthreads();
    const int wave = t >> 6, lane = t & 63;
    for (int base = blockIdx.x * 4; base < rows; base += gridDim.x * 4) {
        int r = base + wave;
        if (r >= rows) continue;
        int v = ag_load_i(&list[r]);
        size_t off = (size_t)v * NF;

        float x0, x1;
        if (AG_IN) {
            x0 = ag_load_f(&Xin[off + lane]);
            x1 = ag_load_f(&Xin[off + lane + 64]);
        } else {
            x0 = Xin[off + lane];
            x1 = Xin[off + lane + 64];
        }
        if (bias) {
            x0 = fmaxf(x0 + bias[lane],      0.f);
            x1 = fmaxf(x1 + bias[lane + 64], 0.f);
        }

        float a0 = 0.f, a1 = 0.f;
        #pragma unroll 16
        for (int k = 0; k < 64; ++k) {
            float xk = __shfl(x0, k);
            a0 += xk * wsm[k][lane];
            a1 += xk * wsm[k][lane + 64];
        }
        #pragma unroll 16
        for (int k = 0; k < 64; ++k) {
            float xk = __shfl(x1, k);
            a0 += xk * wsm[k + 64][lane];
            a1 += xk * wsm[k + 64][lane + 64];
        }

        ag_store_f(&H[off + lane],      a0);
        ag_store_f(&H[off + lane + 64], a1);
    }
}

// ---- per-edge hit handlers (rare paths) ----
__device__ __forceinline__ void p1_hit(const KArgs& a, int d, int i) {
    if (d == a.last) {
        int s = a.srcp[i];
        int p = atomicAdd(&a.cnt[1], 1);
        if (p < CAP_E3) ag_store_e(&a.E3l[p], make_int2(s, d));
        if (!(atomicOr(&a.mark[s], M2) & M2)) {
            int q = atomicAdd(&a.cnt[0], 1);
            if (q < CAP_F2) ag_store_i(&a.F2[q], s);
            int r = atomicAdd(&a.cnt[3], 1);           // self-edge into E2
            if (r < CAP_E2) ag_store_e(&a.E2l[r], make_int2(s, s));
        }
    }
}

__device__ __forceinline__ void p2_hit(const KArgs& a, int d, int i) {
    if (ag_load_i(&a.mark[d]) & M2) {
        int s = a.srcp[i];
        int p = atomicAdd(&a.cnt[3], 1);
        if (p < CAP_E2) ag_store_e(&a.E2l[p], make_int2(s, d));
        if (!(atomicOr(&a.mark[s], M1) & M1)) {
            int q = atomicAdd(&a.cnt[2], 1);
            if (q < CAP_F1) ag_store_i(&a.F1[q], s);
            int r = atomicAdd(&a.cnt[5], 1);           // self-edge into E1
            if (r < CAP_E1) ag_store_e(&a.E1l[r], make_int2(s, s));
        }
    }
}

__device__ __forceinline__ void p3_hit(const KArgs& a, int d, int i) {
    if (ag_load_i(&a.mark[d]) & M1) {
        int s = a.srcp[i];
        int p = atomicAdd(&a.cnt[5], 1);
        if (p < CAP_E1) ag_store_e(&a.E1l[p], make_int2(s, d));
        if (!(atomicOr(&a.mark[s], M0) & M0)) {
            int q = atomicAdd(&a.cnt[4], 1);
            if (q < CAP_F0) ag_store_i(&a.F0[q], s);
        }
    }
}

__global__ __launch_bounds__(256, 2) void k_fused(KArgs a)
{
    __shared__ float wsm[128][128];   // 64 KB
    const int gtid = blockIdx.x * blockDim.x + threadIdx.x;
    const int gstride = gridDim.x * blockDim.x;
    const int E = a.E;
    int* bar = a.bar;
    const bool vec4 = (((uintptr_t)a.dstp & 15) == 0);
    const int4* d4p = (const int4*)a.dstp;
    const int nq = E >> 2;

    // ---- P1: seed + level-1 scan (dst == last) ----
    if (gtid == 0) {
        if (!(atomicOr(&a.mark[a.last], M2) & M2)) {
            int p = atomicAdd(&a.cnt[0], 1);
            if (p < CAP_F2) ag_store_i(&a.F2[p], a.last);
            int r = atomicAdd(&a.cnt[3], 1);
            if (r < CAP_E2) ag_store_e(&a.E2l[r], make_int2(a.last, a.last));
            int e = atomicAdd(&a.cnt[1], 1);
            if (e < CAP_E3) ag_store_e(&a.E3l[e], make_int2(a.last, a.last));
        }
    }
    if (vec4) {
        for (int q = gtid; q < nq; q += gstride) {
            int4 d4 = d4p[q];
            int i = q << 2;
            p1_hit(a, d4.x, i); p1_hit(a, d4.y, i + 1);
            p1_hit(a, d4.z, i + 2); p1_hit(a, d4.w, i + 3);
        }
        for (int i = (nq << 2) + gtid; i < E; i += gstride) p1_hit(a, a.dstp[i], i);
    } else {
        for (int i = gtid; i < E; i += gstride) p1_hit(a, a.dstp[i], i);
    }
    gbar(&bar[0]);

    // ---- P2: level-2 scan (M2 -> M1) + self-prop F2 into F1 (+E1 self) ----
    {
        int sc = min(ag_load_i(&a.cnt[0]), CAP_F2);
        for (int i = gtid; i < sc; i += gstride) {
            int v = ag_load_i(&a.F2[i]);
            if (!(atomicOr(&a.mark[v], M1) & M1)) {
                int p = atomicAdd(&a.cnt[2], 1);
                if (p < CAP_F1) ag_store_i(&a.F1[p], v);
                int r = atomicAdd(&a.cnt[5], 1);
                if (r < CAP_E1) ag_store_e(&a.E1l[r], make_int2(v, v));
            }
        }
        if (vec4) {
            for (int q = gtid; q < nq; q += gstride) {
                int4 d4 = d4p[q];
                int i = q << 2;
                p2_hit(a, d4.x, i); p2_hit(a, d4.y, i + 1);
                p2_hit(a, d4.z, i + 2); p2_hit(a, d4.w, i + 3);
            }
            for (int i = (nq << 2) + gtid; i < E; i += gstride) p2_hit(a, a.dstp[i], i);
        } else {
            for (int i = gtid; i < E; i += gstride) p2_hit(a, a.dstp[i], i);
        }
    }
    gbar(&bar[1024]);

    // ---- P3: level-3 scan (M1 -> M0) + self-prop F1 into F0 ----
    {
        int sc = min(ag_load_i(&a.cnt[2]), CAP_F1);
        for (int i = gtid; i < sc; i += gstride) {
            int v = ag_load_i(&a.F1[i]);
            if (!(atomicOr(&a.mark[v], M0) & M0)) {
                int p = atomicAdd(&a.cnt[4], 1);
                if (p < CAP_F0) ag_store_i(&a.F0[p], v);
            }
        }
        if (vec4) {
            for (int q = gtid; q < nq; q += gstride) {
                int4 d4 = d4p[q];
                int i = q << 2;
                p3_hit(a, d4.x, i); p3_hit(a, d4.y, i + 1);
                p3_hit(a, d4.z, i + 2); p3_hit(a, d4.w, i + 3);
            }
            for (int i = (nq << 2) + gtid; i < E; i += gstride) p3_hit(a, a.dstp[i], i);
        } else {
            for (int i = gtid; i < E; i += gstride) p3_hit(a, a.dstp[i], i);
        }
    }
    gbar(&bar[2048]);

    // ---- P4: conditional deg scan + AGG zero-init + GEMM1 (W1 in LDS) ----
    {
        if (vec4) {
            for (int q = gtid; q < nq; q += gstride) {
                int4 d4 = d4p[q];
                if (ag_load_i(&a.mark[d4.x])) atomicAdd(&a.deg[d4.x], 1);
                if (ag_load_i(&a.mark[d4.y])) atomicAdd(&a.deg[d4.y], 1);
                if (ag_load_i(&a.mark[d4.z])) atomicAdd(&a.deg[d4.z], 1);
                if (ag_load_i(&a.mark[d4.w])) atomicAdd(&a.deg[d4.w], 1);
            }
            for (int i = (nq << 2) + gtid; i < E; i += gstride) {
                int d = a.dstp[i];
                if (ag_load_i(&a.mark[d])) atomicAdd(&a.deg[d], 1);
            }
        } else {
            for (int i = gtid; i < E; i += gstride) {
                int d = a.dstp[i];
                if (ag_load_i(&a.mark[d])) atomicAdd(&a.deg[d], 1);
            }
        }
        int f1 = min(ag_load_i(&a.cnt[2]), CAP_F1);
        for (int i = gtid; i < f1 * NF; i += gstride)
            ag_store_f(&a.aggA[(size_t)ag_load_i(&a.F1[i >> 7]) * NF + (i & 127)], 0.f);
        int f2 = min(ag_load_i(&a.cnt[0]), CAP_F2);
        for (int i = gtid; i < f2 * NF; i += gstride)
            ag_store_f(&a.aggB[(size_t)ag_load_i(&a.F2[i >> 7]) * NF + (i & 127)], 0.f);
        gemm_rows_lds<false>(a.F0, min(ag_load_i(&a.cnt[4]), CAP_F0),
                             a.x, nullptr, a.W1, a.H, wsm);
    }
    gbar(&bar[3072]);

    // ---- P5: scatter E1 into aggA ----
    {
        int ecnt = min(ag_load_i(&a.cnt[5]), CAP_E1);
        int grp = gtid >> 7, f = gtid & 127, ngrp = gstride >> 7;
        for (int i = grp; i < ecnt; i += ngrp) {
            int2 e = ag_load_e(&a.E1l[i]);
            float w = rsqrtf(1.f + (float)ag_load_i(&a.deg[e.x])) *
                      rsqrtf(1.f + (float)ag_load_i(&a.deg[e.y]));
            atomicAdd(&a.aggA[(size_t)e.y * NF + f],
                      ag_load_f(&a.H[(size_t)e.x * NF + f]) * w);
        }
    }
    gbar(&bar[4096]);

    // ---- P6: GEMM2 on F1 rows: H2 = relu(aggA+b1) @ W2 ----
    gemm_rows_lds<true>(a.F1, min(ag_load_i(&a.cnt[2]), CAP_F1),
                        a.aggA, a.b1, a.W2, a.H, wsm);
    gbar(&bar[5120]);

    // ---- P7: scatter E2 into aggB (grid-wide, ~180 edges) ----
    {
        int ecnt = min(ag_load_i(&a.cnt[3]), CAP_E2);
        int grp = gtid >> 7, f = gtid & 127, ngrp = gstride >> 7;
        for (int i = grp; i < ecnt; i += ngrp) {
            int2 e = ag_load_e(&a.E2l[i]);
            float w = rsqrtf(1.f + (float)ag_load_i(&a.deg[e.x])) *
                      rsqrtf(1.f + (float)ag_load_i(&a.deg[e.y]));
            atomicAdd(&a.aggB[(size_t)e.y * NF + f],
                      ag_load_f(&a.H[(size_t)e.x * NF + f]) * w);
        }
    }
    gbar(&bar[6144]);

    // ---- P8 (block 0 only): GEMM3 (~13 rows) + E3 register-reduce + FC ----
    if (blockIdx.x == 0) {
        const int t = threadIdx.x;
        {
            const float4* W4 = (const float4*)a.W3;
            float4* S4 = (float4*)&wsm[0][0];
            #pragma unroll
            for (int it = 0; it < 16; ++it) S4[it * 256 + t] = W4[it * 256 + t];
        }
        __syncthreads();
        const int wave = t >> 6, lane = t & 63;
        int rows = min(ag_load_i(&a.cnt[0]), CAP_F2);
        for (int r = wave; r < rows; r += 4) {
            int v = ag_load_i(&a.F2[r]);
            size_t off = (size_t)v * NF;
            float x0 = fmaxf(ag_load_f(&a.aggB[off + lane])      + a.b2[lane],      0.f);
            float x1 = fmaxf(ag_load_f(&a.aggB[off + lane + 64]) + a.b2[lane + 64], 0.f);
            float a0 = 0.f, a1 = 0.f;
            #pragma unroll 16
            for (int k = 0; k < 64; ++k) {
                float xk = __shfl(x0, k);
                a0 += xk * wsm[k][lane];
                a1 += xk * wsm[k][lane + 64];
            }
            #pragma unroll 16
            for (int k = 0; k < 64; ++k) {
                float xk = __shfl(x1, k);
                a0 += xk * wsm[k + 64][lane];
                a1 += xk * wsm[k + 64][lane + 64];
            }
            ag_store_f(&a.H[off + lane],      a0);
            ag_store_f(&a.H[off + lane + 64], a1);
        }
        __syncthreads();
        if (t < NF) {
            float dl = rsqrtf(1.f + (float)ag_load_i(&a.deg[a.last]));
            float acc = 0.f;
            int e3 = min(ag_load_i(&a.cnt[1]), CAP_E3);
            for (int i = 0; i < e3; ++i) {
                int s = ag_load_e(&a.E3l[i]).x;
                acc += rsqrtf(1.f + (float)ag_load_i(&a.deg[s])) * dl *
                       ag_load_f(&a.H[(size_t)s * NF + t]);
            }
            wsm[0][t] = fmaxf(acc + a.b3[t], 0.f);
        }
        __syncthreads();
        if (t < OUTF) {
            float acc = a.fcb[t];
            #pragma unroll 16
            for (int k = 0; k < NF; ++k) acc += wsm[0][k] * a.fcW[k * OUTF + t];
            a.out[t] = acc;
        }
    }
}

// ---------------------------------------------------------------------------
// Fallback: proven multi-kernel pipeline (used only if coop launch rejected)
// ---------------------------------------------------------------------------

__global__ void k_seed(int* __restrict__ mark, int* __restrict__ F2,
                       int* __restrict__ cnt, int last) {
    if (threadIdx.x == 0) {
        mark[last] = M2;
        F2[0] = last;
        cnt[0] = 1;
    }
}

__global__ void k_mark(const int* __restrict__ src, const int* __restrict__ dst, int E,
                       int* __restrict__ mark, int checkBit, int setBit, int last,
                       int2* __restrict__ Elist, int Ecap, int* __restrict__ eCnt,
                       int* __restrict__ Flist, int Fcap, int* __restrict__ fCnt,
                       const int* __restrict__ selfList, const int* __restrict__ selfCnt,
                       int selfCap)
{
    int i = blockIdx.x * blockDim.x + threadIdx.x;

    if (selfList) {
        int sc = *selfCnt; if (sc > selfCap) sc = selfCap;
        if (i < sc) {
            int v = selfList[i];
            if (!(atomicOr(&mark[v], setBit) & setBit)) {
                int p = atomicAdd(fCnt, 1);
                if (p < Fcap) Flist[p] = v;
            }
        }
    }
    if (i < E) {
        int d = dst[i];
        bool hit = checkBit ? ((mark[d] & checkBit) != 0) : (d == last);
        if (hit) {
            int s = src[i];
            int p = atomicAdd(eCnt, 1);
            if (p < Ecap) Elist[p] = make_int2(s, d);
            if (!(atomicOr(&mark[s], setBit) & setBit)) {
                int q = atomicAdd(fCnt, 1);
                if (q < Fcap) Flist[q] = s;
            }
        }
    }
}

__global__ void k_degm(const int* __restrict__ dst, const int* __restrict__ mark,
                       int* __restrict__ deg, int E) {
    int i = blockIdx.x * blockDim.x + threadIdx.x;
    if (i < E) {
        int d = dst[i];
        if (mark[d]) atomicAdd(&deg[d], 1);
    }
}

__global__ void k_dinvm(const int* __restrict__ mark, const int* __restrict__ deg,
                        float* __restrict__ dinv, int n) {
    int i = blockIdx.x * blockDim.x + threadIdx.x;
    if (i < n && mark[i]) dinv[i] = rsqrtf(1.0f + (float)deg[i]);
}

__global__ __launch_bounds__(256) void k_gemm_rows(
    const int* __restrict__ list, const int* __restrict__ cntPtr, int cap,
    const float* __restrict__ Xin, const float* __restrict__ bias,
    const float* __restrict__ W, const float* __restrict__ dinv,
    const int* __restrict__ mark, int aggBit, int last,
    float* __restrict__ H, float* __restrict__ AGG)
{
    __shared__ float wsm[128][128];
    const int t = threadIdx.x;

    {
        const float4* W4 = (const float4*)W;
        float4* S4 = (float4*)&wsm[0][0];
        #pragma unroll
        for (int it = 0; it < 16; ++it) S4[it * 256 + t] = W4[it * 256 + t];
    }
    __syncthreads();

    int cnt = *cntPtr; if (cnt > cap) cnt = cap;
    const int wave = t >> 6, lane = t & 63;

    for (int base = blockIdx.x * 4; base < cnt; base += gridDim.x * 4) {
        int r = base + wave;
        if (r >= cnt) continue;
        int v = list[r];
        size_t off = (size_t)v * NF;

        float x0, x1;
        if (bias) {
            x0 = fmaxf(Xin[off + lane]      + bias[lane],      0.f);
            x1 = fmaxf(Xin[off + lane + 64] + bias[lane + 64], 0.f);
        } else {
            x0 = Xin[off + lane];
            x1 = Xin[off + lane + 64];
        }

        float a0 = 0.f, a1 = 0.f;
        #pragma unroll 16
        for (int k = 0; k < 64; ++k) {
            float xk = __shfl(x0, k);
            a0 += xk * wsm[k][lane];
            a1 += xk * wsm[k][lane + 64];
        }
        #pragma unroll 16
        for (int k = 0; k < 64; ++k) {
            float xk = __shfl(x1, k);
            a0 += xk * wsm[k + 64][lane];
            a1 += xk * wsm[k + 64][lane + 64];
        }

        H[off + lane]      = a0;
        H[off + lane + 64] = a1;

        bool doAgg = (mark ? ((mark[v] & aggBit) != 0) : false) || (v == last);
        if (doAgg) {
            float di = dinv[v], s2 = di * di;
            AGG[off + lane]      = a0 * s2;
            AGG[off + lane + 64] = a1 * s2;
        }
    }
}

__global__ void k_scat(const int2* __restrict__ list, const int* __restrict__ cntPtr, int cap,
                       const float* __restrict__ dinv, const float* __restrict__ H,
                       float* __restrict__ AGG)
{
    int cnt = *cntPtr; if (cnt > cap) cnt = cap;
    int t = threadIdx.x;
    for (int i = blockIdx.x; i < cnt; i += gridDim.x) {
        int2 e = list[i];
        float w = dinv[e.x] * dinv[e.y];
        atomicAdd(&AGG[(size_t)e.y * NF + t], H[(size_t)e.x * NF + t] * w);
    }
}

__global__ void k_fc(const float* __restrict__ AGG3, const float* __restrict__ b3,
                     const float* __restrict__ fcW, const float* __restrict__ fcb,
                     float* __restrict__ out, int last)
{
    __shared__ float xrow[NF];
    int j = threadIdx.x;
    size_t off = (size_t)last * NF;
    xrow[j]      = fmaxf(AGG3[off + j]      + b3[j],      0.f);
    xrow[j + 64] = fmaxf(AGG3[off + j + 64] + b3[j + 64], 0.f);
    __syncthreads();
    float acc = fcb[j];
    #pragma unroll 16
    for (int k = 0; k < NF; ++k) acc += xrow[k] * fcW[k * OUTF + j];
    out[j] = acc;
}

// ---------------------------------------------------------------------------

extern "C" void kernel_launch(void* const* d_in, const int* in_sizes, int n_in,
                              void* d_out, int out_size, void* d_ws, size_t ws_size,
                              hipStream_t stream)
{
    const float* x    = (const float*)d_in[0];
    const int*   ei   = (const int*)d_in[1];
    const float* W1   = (const float*)d_in[2];
    const float* b1   = (const float*)d_in[3];
    const float* W2   = (const float*)d_in[4];
    const float* b2   = (const float*)d_in[5];
    const float* W3   = (const float*)d_in[6];
    const float* b3   = (const float*)d_in[7];
    const float* fcW  = (const float*)d_in[8];
    const float* fcb  = (const float*)d_in[9];
    float* out = (float*)d_out;

    const int n = in_sizes[0] / NF;       // 50000
    const int E = in_sizes[1] / 2;        // 600000
    const int* src = ei;
    const int* dst = ei + E;
    const int last = n - 1;

    char* wp = (char*)d_ws;
    auto alloc = [&](size_t bytes) -> void* {
        void* r = (void*)wp;
        wp += (bytes + 255) & ~(size_t)255;
        return r;
    };
    // zeroed region: deg | mark | cnt+barriers  (one memset)
    int*   deg  = (int*)alloc((size_t)n * 4);
    int*   mark = (int*)alloc((size_t)n * 4);
    int*   cnt  = (int*)alloc((64 + 8 * 1024) * 4);   // counters + 8 barrier blocks
    size_t zbytes = (char*)wp - (char*)deg;

    float* dinv = (float*)alloc((size_t)n * 4);      // fallback path only
    int*   F2   = (int*) alloc(CAP_F2 * 4);
    int2*  E3   = (int2*)alloc(CAP_E3 * 8);
    int*   F1   = (int*) alloc(CAP_F1 * 4);
    int2*  E2   = (int2*)alloc(CAP_E2 * 8);
    int*   F0   = (int*) alloc(CAP_F0 * 4);
    int2*  E1   = (int2*)alloc(CAP_E1 * 8);
    float* H    = (float*)alloc((size_t)n * NF * 4);
    float* aggA = (float*)alloc((size_t)n * NF * 4);
    float* aggB = (float*)alloc((size_t)n * NF * 4);

    // ---- single fused kernel (cooperative launch for co-residency) ----
    static int coopState = -2;   // -2 untested, -1 unsupported, >0 grid size
    if (coopState != -1) {
        if (coopState == -2) {
            int perCU = 0;
            if (hipOccupancyMaxActiveBlocksPerMultiprocessor(&perCU, k_fused, 256, 0)
                    != hipSuccess || perCU < 1)
                perCU = 1;
            long g = (long)perCU * 256;   // 256 CUs on MI355X
            if (g > 512) g = 512;         // 64KB LDS -> 2 blocks/CU max
            coopState = (int)g;
        }
        KArgs ha;
        ha.x = x; ha.srcp = src; ha.dstp = dst;
        ha.E = E; ha.n = n; ha.last = last;
        ha.W1 = W1; ha.b1 = b1; ha.W2 = W2; ha.b2 = b2;
        ha.W3 = W3; ha.b3 = b3; ha.fcW = fcW; ha.fcb = fcb;
        ha.deg = deg; ha.mark = mark; ha.cnt = cnt; ha.bar = cnt + 64;
        ha.F2 = F2; ha.E3l = E3; ha.F1 = F1; ha.E2l = E2; ha.F0 = F0; ha.E1l = E1;
        ha.H = H; ha.aggA = aggA; ha.aggB = aggB; ha.out = out;

        hipMemsetAsync(deg, 0, zbytes, stream);   // zeros deg, mark, cnt, barriers
        void* params[1] = { (void*)&ha };
        hipError_t err = hipLaunchCooperativeKernel(k_fused, dim3(coopState), dim3(256),
                                                    params, 0u, stream);
        if (err == hipSuccess) return;
        coopState = -1;          // coop not available; use fallback
        (void)hipGetLastError();
    }

    // ---- fallback: original multi-kernel pipeline ----
    const int B  = 256;
    const int EB = (E + B - 1) / B;
    const int NB = (n + B - 1) / B;

    hipMemsetAsync(deg, 0, zbytes, stream);
    k_seed<<<1, 64, 0, stream>>>(mark, F2, cnt, last);

    k_mark<<<EB, B, 0, stream>>>(src, dst, E, mark, 0,  M2, last,
                                 E3, CAP_E3, &cnt[1], F2, CAP_F2, &cnt[0],
                                 nullptr, nullptr, 0);
    k_mark<<<EB, B, 0, stream>>>(src, dst, E, mark, M2, M1, last,
                                 E2, CAP_E2, &cnt[3], F1, CAP_F1, &cnt[2],
                                 F2, &cnt[0], CAP_F2);
    k_mark<<<EB, B, 0, stream>>>(src, dst, E, mark, M1, M0, last,
                                 E1, CAP_E1, &cnt[5], F0, CAP_F0, &cnt[4],
                                 F1, &cnt[2], CAP_F1);

    k_degm <<<EB, B, 0, stream>>>(dst, mark, deg, E);
    k_dinvm<<<NB, B, 0, stream>>>(mark, deg, dinv, n);

    k_gemm_rows<<<384, B, 0, stream>>>(F0, &cnt[4], CAP_F0, x, nullptr, W1,
                                       dinv, mark, M1, -1, H, aggA);
    k_scat<<<2048, 128, 0, stream>>>(E1, &cnt[5], CAP_E1, dinv, H, aggA);

    k_gemm_rows<<<384, B, 0, stream>>>(F1, &cnt[2], CAP_F1, aggA, b1, W2,
                                       dinv, mark, M2, -1, H, aggB);
    k_scat<<<2048, 128, 0, stream>>>(E2, &cnt[3], CAP_E2, dinv, H, aggB);

    k_gemm_rows<<<384, B, 0, stream>>>(F2, &cnt[0], CAP_F2, aggB, b2, W3,
                                       dinv, nullptr, 0, last, H, aggA);
    k_scat<<<2048, 128, 0, stream>>>(E3, &cnt[1], CAP_E3, dinv, H, aggA);

    k_fc<<<1, 64, 0, stream>>>(aggA, b3, fcW, fcb, out, last);
}